// Round 1
// baseline (18201.291 us; speedup 1.0000x reference)
//
#include <hip/hip_runtime.h>

#define BB 16
#define SS 128
#define DD 768
#define HH 12
#define DKK 64
#define DFFF 3072
#define NLL 6
#define SRCC 256

// ---------------- positional encoding table ----------------
__global__ void pe_build_k(float* __restrict__ pe) {
  int idx = blockIdx.x * blockDim.x + threadIdx.x;
  if (idx >= SS * (DD / 2)) return;
  int s = idx / (DD / 2);
  int i = idx - s * (DD / 2);
  float div = expf((float)(2 * i) * (-logf(10000.0f) / (float)DD));
  float ang = (float)s * div;
  pe[s * DD + 2 * i]     = sinf(ang);
  pe[s * DD + 2 * i + 1] = cosf(ang);
}

// ---------------- x = emb[trg] + alpha * pe ----------------
__global__ void embed_k(const int* __restrict__ trg, const float* __restrict__ emb,
                        const float* __restrict__ pe, const float* __restrict__ alpha,
                        float* __restrict__ x) {
  int idx = blockIdx.x * blockDim.x + threadIdx.x;  // over B*S*(D/4)
  int c = idx % (DD / 4);
  int r = idx / (DD / 4);
  if (r >= BB * SS) return;
  int s = r % SS;
  float al = alpha[0];
  float4 e = *(const float4*)(emb + (size_t)trg[r] * DD + c * 4);
  float4 p = *(const float4*)(pe + (size_t)s * DD + c * 4);
  float4 o;
  o.x = e.x + al * p.x; o.y = e.y + al * p.y;
  o.z = e.z + al * p.z; o.w = e.w + al * p.w;
  *(float4*)(x + (size_t)r * DD + c * 4) = o;
}

// ---------------- y = broadcast(y_param) ----------------
__global__ void yinit_k(const float* __restrict__ yp, float* __restrict__ y) {
  int idx = blockIdx.x * blockDim.x + threadIdx.x;  // over B*S*(D/4)
  int c = idx % (DD / 4);
  int r = idx / (DD / 4);
  if (r >= BB * SS) return;
  int s = r % SS;
  *(float4*)(y + (size_t)r * DD + c * 4) = *(const float4*)(yp + (size_t)s * DD + c * 4);
}

// ---------------- combined mask cutoff r[b] ----------------
__global__ void mask_k(const int* __restrict__ trg, int* __restrict__ rbuf) {
  if (threadIdx.x != 0 || blockIdx.x != 0) return;
  int cm[BB];
  int cmin = 0x7fffffff;
  for (int b = 0; b < BB; b++) {
    int start = 0;
    for (int s = 0; s < SS; s++) {
      if (trg[b * SS + s] == 0) { start = s; break; }
    }
    int c = (start == 0) ? (SS + 1) : start;
    cmin = min(cmin, c);
    cm[b] = cmin;
  }
  for (int b = 0; b < BB; b++) rbuf[b] = cm[min(b, BB - 2)];
}

// ---------------- LayerNorm (row = blockIdx.x), D=768, 256 thr ----------------
__global__ __launch_bounds__(256) void ln_k(const float* __restrict__ x,
                                            const float* __restrict__ ga,
                                            const float* __restrict__ gb,
                                            float* __restrict__ out) {
  __shared__ float sm[8];
  int row = blockIdx.x;
  int t = threadIdx.x;
  const float* xr = x + (size_t)row * DD;
  float v0 = xr[t], v1 = xr[t + 256], v2 = xr[t + 512];
  float s = v0 + v1 + v2;
#pragma unroll
  for (int o = 32; o > 0; o >>= 1) s += __shfl_down(s, o);
  if ((t & 63) == 0) sm[t >> 6] = s;
  __syncthreads();
  float mean = (sm[0] + sm[1] + sm[2] + sm[3]) * (1.0f / (float)DD);
  float d0 = v0 - mean, d1 = v1 - mean, d2 = v2 - mean;
  float q = d0 * d0 + d1 * d1 + d2 * d2;
#pragma unroll
  for (int o = 32; o > 0; o >>= 1) q += __shfl_down(q, o);
  if ((t & 63) == 0) sm[4 + (t >> 6)] = q;
  __syncthreads();
  float var = (sm[4] + sm[5] + sm[6] + sm[7]) * (1.0f / (float)DD);
  float inv = 1.0f / sqrtf(var + 1e-6f);
  float* orow = out + (size_t)row * DD;
  orow[t]       = ga[t] * d0 * inv + gb[t];
  orow[t + 256] = ga[t + 256] * d1 * inv + gb[t + 256];
  orow[t + 512] = ga[t + 512] * d2 * inv + gb[t + 512];
}

// ---------------- f32 tiled GEMM: C = [res +] A@W + bias, opt ReLU ----------------
// A: [M][K], W: [K][N], 64x64 tile per block, 256 threads, 4x4 per thread.
__global__ __launch_bounds__(256) void gemm_k(const float* __restrict__ A,
                                              const float* __restrict__ W,
                                              const float* __restrict__ bias,
                                              const float* __restrict__ res,
                                              float* __restrict__ C,
                                              int M, int N, int K, int relu) {
  __shared__ float As[16][64];
  __shared__ float Bs[16][64];
  int t = threadIdx.x;
  int tx = t & 15, ty = t >> 4;
  int m0 = blockIdx.y * 64, n0 = blockIdx.x * 64;
  int mA = t >> 2, kA = (t & 3) * 4;
  int kB = t >> 4, nB = (t & 15) * 4;
  const float* Ap = A + (size_t)(m0 + mA) * K + kA;
  const float* Wp = W + (size_t)kB * N + n0 + nB;
  float acc[4][4] = {};
  for (int k0 = 0; k0 < K; k0 += 16) {
    float4 av = *(const float4*)(Ap + k0);
    float4 bv = *(const float4*)(Wp + (size_t)k0 * N);
    As[kA + 0][mA] = av.x; As[kA + 1][mA] = av.y;
    As[kA + 2][mA] = av.z; As[kA + 3][mA] = av.w;
    *(float4*)&Bs[kB][nB] = bv;
    __syncthreads();
#pragma unroll
    for (int k = 0; k < 16; k++) {
      float4 a = *(const float4*)&As[k][ty * 4];
      float4 b = *(const float4*)&Bs[k][tx * 4];
      acc[0][0] += a.x * b.x; acc[0][1] += a.x * b.y; acc[0][2] += a.x * b.z; acc[0][3] += a.x * b.w;
      acc[1][0] += a.y * b.x; acc[1][1] += a.y * b.y; acc[1][2] += a.y * b.z; acc[1][3] += a.y * b.w;
      acc[2][0] += a.z * b.x; acc[2][1] += a.z * b.y; acc[2][2] += a.z * b.z; acc[2][3] += a.z * b.w;
      acc[3][0] += a.w * b.x; acc[3][1] += a.w * b.y; acc[3][2] += a.w * b.z; acc[3][3] += a.w * b.w;
    }
    __syncthreads();
  }
#pragma unroll
  for (int i = 0; i < 4; i++) {
    int m = m0 + ty * 4 + i;
    size_t base = (size_t)m * N + n0 + tx * 4;
    float4 o;
    o.x = acc[i][0] + bias[n0 + tx * 4 + 0];
    o.y = acc[i][1] + bias[n0 + tx * 4 + 1];
    o.z = acc[i][2] + bias[n0 + tx * 4 + 2];
    o.w = acc[i][3] + bias[n0 + tx * 4 + 3];
    if (res) {
      float4 rv = *(const float4*)(res + base);
      o.x += rv.x; o.y += rv.y; o.z += rv.z; o.w += rv.w;
    }
    if (relu) {
      o.x = fmaxf(o.x, 0.f); o.y = fmaxf(o.y, 0.f);
      o.z = fmaxf(o.z, 0.f); o.w = fmaxf(o.w, 0.f);
    }
    *(float4*)(C + base) = o;
  }
}

// ---------------- fused attention: scores -> softmax -> PV ----------------
// grid = B*H*(S/16); block 256. mode: 0=causal+r cutoff, 1=src_mask, 2=none.
template <int SK>
__global__ __launch_bounds__(256) void attn_k(const float* __restrict__ qb,
                                              const float* __restrict__ kb,
                                              const float* __restrict__ vb,
                                              float* __restrict__ ctx, int mode,
                                              const int* __restrict__ rbuf,
                                              const int* __restrict__ smask) {
  __shared__ float qs[16][64];
  __shared__ float ps[16][SK];
  int bid = blockIdx.x;
  int qt = bid & 7;              // S/16 = 8
  int h = (bid >> 3) % HH;
  int b = bid / (8 * HH);
  int t = threadIdx.x;
  {
    int row = t >> 4, c4 = (t & 15) * 4;
    *(float4*)&qs[row][c4] =
        *(const float4*)(qb + (size_t)(b * SS + qt * 16 + row) * DD + h * DKK + c4);
  }
  __syncthreads();
  int qi = t >> 4, kk = t & 15;
  int qg = qt * 16 + qi;
  float sc[SK / 16];
#pragma unroll
  for (int j = 0; j < SK / 16; j++) {
    int k = kk + 16 * j;
    const float* kr = kb + (size_t)(b * SK + k) * DD + h * DKK;
    float s = 0.f;
#pragma unroll
    for (int d4 = 0; d4 < 16; d4++) {
      float4 kv = *(const float4*)(kr + d4 * 4);
      float4 qv = *(const float4*)&qs[qi][d4 * 4];
      s += qv.x * kv.x + qv.y * kv.y + qv.z * kv.z + qv.w * kv.w;
    }
    s *= 0.125f;  // 1/sqrt(64)
    bool keep = true;
    if (mode == 0) keep = (k <= qg) && (qg < rbuf[b]);
    else if (mode == 1) keep = (smask[b * SRCC + k] != 0);
    sc[j] = keep ? s : -1e9f;
  }
  // softmax across the 16-lane group x (SK/16) regs
  float m = -3.4e38f;
#pragma unroll
  for (int j = 0; j < SK / 16; j++) m = fmaxf(m, sc[j]);
#pragma unroll
  for (int o = 1; o < 16; o <<= 1) m = fmaxf(m, __shfl_xor(m, o));
  float sum = 0.f;
#pragma unroll
  for (int j = 0; j < SK / 16; j++) { sc[j] = expf(sc[j] - m); sum += sc[j]; }
#pragma unroll
  for (int o = 1; o < 16; o <<= 1) sum += __shfl_xor(sum, o);
  float rinv = 1.0f / sum;
#pragma unroll
  for (int j = 0; j < SK / 16; j++) ps[qi][kk + 16 * j] = sc[j] * rinv;
  __syncthreads();
  {
    int qi2 = t >> 4, d = (t & 15) * 4;
    float4 acc = make_float4(0.f, 0.f, 0.f, 0.f);
    for (int k = 0; k < SK; k++) {
      float p = ps[qi2][k];
      float4 vv = *(const float4*)(vb + (size_t)(b * SK + k) * DD + h * DKK + d);
      acc.x += p * vv.x; acc.y += p * vv.y; acc.z += p * vv.z; acc.w += p * vv.w;
    }
    *(float4*)(ctx + (size_t)(b * SS + qt * 16 + qi2) * DD + h * DKK + d) = acc;
  }
}

// ---------------- launch ----------------
extern "C" void kernel_launch(void* const* d_in, const int* in_sizes, int n_in,
                              void* d_out, int out_size, void* d_ws, size_t ws_size,
                              hipStream_t stream) {
  const int*   trg   = (const int*)d_in[0];
  const float* e_out = (const float*)d_in[1];
  const int*   smask = (const int*)d_in[2];
  const float* emb   = (const float*)d_in[3];
  const float* ypar  = (const float*)d_in[4];
  const float* alpha = (const float*)d_in[5];
  const float* Wq = (const float*)d_in[6];
  const float* Wk = (const float*)d_in[7];
  const float* Wv = (const float*)d_in[8];
  const float* Wo = (const float*)d_in[9];
  const float* bq = (const float*)d_in[10];
  const float* bk = (const float*)d_in[11];
  const float* bv = (const float*)d_in[12];
  const float* bo = (const float*)d_in[13];
  const float* W1 = (const float*)d_in[14];
  const float* b1 = (const float*)d_in[15];
  const float* W2 = (const float*)d_in[16];
  const float* b2 = (const float*)d_in[17];
  const float* lna = (const float*)d_in[18];
  const float* lnb = (const float*)d_in[19];
  const float* fa = (const float*)d_in[20];
  const float* fb = (const float*)d_in[21];
  float* out = (float*)d_out;

  float* ws = (float*)d_ws;
  size_t off = 0;
  float* pe = ws + off;  off += (size_t)SS * DD;        // 98304
  int* rbuf = (int*)(ws + off); off += 64;
  float* x   = ws + off; off += (size_t)BB * SS * DD;
  float* y   = ws + off; off += (size_t)BB * SS * DD;
  float* x2  = ws + off; off += (size_t)BB * SS * DD;
  float* y3  = ws + off; off += (size_t)BB * SS * DD;
  float* qb  = ws + off; off += (size_t)BB * SS * DD;
  float* kb  = ws + off; off += (size_t)BB * SRCC * DD;
  float* vb  = ws + off; off += (size_t)BB * SRCC * DD;
  float* ctx = ws + off; off += (size_t)BB * SS * DD;
  float* mid = ws + off; off += (size_t)BB * SS * DFFF;
  if (ws_size < off * sizeof(float)) return;  // workspace too small: bail

  pe_build_k<<<(SS * (DD / 2) + 255) / 256, 256, 0, stream>>>(pe);
  embed_k<<<(BB * SS * (DD / 4) + 255) / 256, 256, 0, stream>>>(trg, emb, pe, alpha, x);
  yinit_k<<<(BB * SS * (DD / 4) + 255) / 256, 256, 0, stream>>>(ypar, y);
  mask_k<<<1, 64, 0, stream>>>(trg, rbuf);

  auto GEMM = [&](const float* A, int M, int K, const float* W, int N,
                  const float* bias, const float* res, float* C, int relu) {
    gemm_k<<<dim3(N / 64, M / 64), 256, 0, stream>>>(A, W, bias, res, C, M, N, K, relu);
  };

  const int nattn = BB * HH * (SS / 16);

  for (int l = 0; l < NLL; l++) {
    const float* wq[3], *wk[3], *wv[3], *wo[3], *bql[3], *bkl[3], *bvl[3], *bol[3];
    for (int j = 0; j < 3; j++) {
      size_t wOff = ((size_t)l * 3 + j) * DD * DD;
      size_t bOff = ((size_t)l * 3 + j) * DD;
      wq[j] = Wq + wOff; wk[j] = Wk + wOff; wv[j] = Wv + wOff; wo[j] = Wo + wOff;
      bql[j] = bq + bOff; bkl[j] = bk + bOff; bvl[j] = bv + bOff; bol[j] = bo + bOff;
    }
    auto LN = [&](const float* in, int slot, float* o) {
      ln_k<<<BB * SS, 256, 0, stream>>>(in, lna + ((size_t)l * 5 + slot) * DD,
                                        lnb + ((size_t)l * 5 + slot) * DD, o);
    };
    // ---- MHA1: self-attn on x (causal + cutoff mask) ----
    LN(x, 0, x2);
    GEMM(x2, BB * SS, DD, wq[0], DD, bql[0], nullptr, qb, 0);
    GEMM(x2, BB * SS, DD, wk[0], DD, bkl[0], nullptr, kb, 0);
    GEMM(x2, BB * SS, DD, wv[0], DD, bvl[0], nullptr, vb, 0);
    attn_k<SS><<<nattn, 256, 0, stream>>>(qb, kb, vb, ctx, 0, rbuf, nullptr);
    GEMM(ctx, BB * SS, DD, wo[0], DD, bol[0], x, x, 0);
    // ---- MHA2: y cross-attends e_outputs (src mask) ----
    LN(y, 1, x2);
    GEMM(x2, BB * SS, DD, wq[1], DD, bql[1], nullptr, qb, 0);
    GEMM(e_out, BB * SRCC, DD, wk[1], DD, bkl[1], nullptr, kb, 0);
    GEMM(e_out, BB * SRCC, DD, wv[1], DD, bvl[1], nullptr, vb, 0);
    attn_k<SRCC><<<nattn, 256, 0, stream>>>(qb, kb, vb, ctx, 1, nullptr, smask);
    GEMM(ctx, BB * SS, DD, wo[1], DD, bol[1], y, y, 0);
    // ---- MHA3: x cross-attends ln(y) (no mask) ----
    LN(x, 2, x2);
    LN(y, 3, y3);
    GEMM(x2, BB * SS, DD, wq[2], DD, bql[2], nullptr, qb, 0);
    GEMM(y3, BB * SS, DD, wk[2], DD, bkl[2], nullptr, kb, 0);
    GEMM(y3, BB * SS, DD, wv[2], DD, bvl[2], nullptr, vb, 0);
    attn_k<SS><<<nattn, 256, 0, stream>>>(qb, kb, vb, ctx, 2, nullptr, nullptr);
    GEMM(ctx, BB * SS, DD, wo[2], DD, bol[2], x, x, 0);
    // ---- FFN ----
    LN(x, 4, x2);
    GEMM(x2, BB * SS, DD, W1 + (size_t)l * DD * DFFF, DFFF, b1 + (size_t)l * DFFF,
         nullptr, mid, 1);
    GEMM(mid, BB * SS, DFFF, W2 + (size_t)l * DFFF * DD, DD, b2 + (size_t)l * DD, x, x, 0);
  }
  ln_k<<<BB * SS, 256, 0, stream>>>(x, fa, fb, out);
}

// Round 2
// 7922.366 us; speedup vs baseline: 2.2975x; 2.2975x over previous
//
#include <hip/hip_runtime.h>

#define BB 16
#define SS 128
#define DD 768
#define HH 12
#define DKK 64
#define DFFF 3072
#define NLL 6
#define SRCC 256

// ---------------- positional encoding table ----------------
__global__ void pe_build_k(float* __restrict__ pe) {
  int idx = blockIdx.x * blockDim.x + threadIdx.x;
  if (idx >= SS * (DD / 2)) return;
  int s = idx / (DD / 2);
  int i = idx - s * (DD / 2);
  float div = expf((float)(2 * i) * (-logf(10000.0f) / (float)DD));
  float ang = (float)s * div;
  pe[s * DD + 2 * i]     = sinf(ang);
  pe[s * DD + 2 * i + 1] = cosf(ang);
}

// ---------------- x = emb[trg] + alpha * pe ----------------
__global__ void embed_k(const int* __restrict__ trg, const float* __restrict__ emb,
                        const float* __restrict__ pe, const float* __restrict__ alpha,
                        float* __restrict__ x) {
  int idx = blockIdx.x * blockDim.x + threadIdx.x;  // over B*S*(D/4)
  int c = idx % (DD / 4);
  int r = idx / (DD / 4);
  if (r >= BB * SS) return;
  int s = r % SS;
  float al = alpha[0];
  float4 e = *(const float4*)(emb + (size_t)trg[r] * DD + c * 4);
  float4 p = *(const float4*)(pe + (size_t)s * DD + c * 4);
  float4 o;
  o.x = e.x + al * p.x; o.y = e.y + al * p.y;
  o.z = e.z + al * p.z; o.w = e.w + al * p.w;
  *(float4*)(x + (size_t)r * DD + c * 4) = o;
}

// ---------------- y = broadcast(y_param) ----------------
__global__ void yinit_k(const float* __restrict__ yp, float* __restrict__ y) {
  int idx = blockIdx.x * blockDim.x + threadIdx.x;  // over B*S*(D/4)
  int c = idx % (DD / 4);
  int r = idx / (DD / 4);
  if (r >= BB * SS) return;
  int s = r % SS;
  *(float4*)(y + (size_t)r * DD + c * 4) = *(const float4*)(yp + (size_t)s * DD + c * 4);
}

// ---------------- combined mask cutoff r[b] ----------------
__global__ void mask_k(const int* __restrict__ trg, int* __restrict__ rbuf) {
  if (threadIdx.x != 0 || blockIdx.x != 0) return;
  int cmin = 0x7fffffff;
  int cm[BB];
  for (int b = 0; b < BB; b++) {
    int start = 0;
    for (int s = 0; s < SS; s++) {
      if (trg[b * SS + s] == 0) { start = s; break; }
    }
    int c = (start == 0) ? (SS + 1) : start;
    cmin = min(cmin, c);
    cm[b] = cmin;
  }
  for (int b = 0; b < BB; b++) rbuf[b] = cm[min(b, BB - 2)];
}

// ---------------- LayerNorm (row = blockIdx.x), D=768, 256 thr ----------------
__global__ __launch_bounds__(256) void ln_k(const float* __restrict__ x,
                                            const float* __restrict__ ga,
                                            const float* __restrict__ gb,
                                            float* __restrict__ out) {
  __shared__ float sm[8];
  int row = blockIdx.x;
  int t = threadIdx.x;
  const float* xr = x + (size_t)row * DD;
  float v0 = xr[t], v1 = xr[t + 256], v2 = xr[t + 512];
  float s = v0 + v1 + v2;
#pragma unroll
  for (int o = 32; o > 0; o >>= 1) s += __shfl_down(s, o);
  if ((t & 63) == 0) sm[t >> 6] = s;
  __syncthreads();
  float mean = (sm[0] + sm[1] + sm[2] + sm[3]) * (1.0f / (float)DD);
  float d0 = v0 - mean, d1 = v1 - mean, d2 = v2 - mean;
  float q = d0 * d0 + d1 * d1 + d2 * d2;
#pragma unroll
  for (int o = 32; o > 0; o >>= 1) q += __shfl_down(q, o);
  if ((t & 63) == 0) sm[4 + (t >> 6)] = q;
  __syncthreads();
  float var = (sm[4] + sm[5] + sm[6] + sm[7]) * (1.0f / (float)DD);
  float inv = 1.0f / sqrtf(var + 1e-6f);
  float* orow = out + (size_t)row * DD;
  orow[t]       = ga[t] * d0 * inv + gb[t];
  orow[t + 256] = ga[t + 256] * d1 * inv + gb[t + 256];
  orow[t + 512] = ga[t + 512] * d2 * inv + gb[t + 512];
}

// ---------------- f32 tiled GEMM: C = [res +] A@W + bias, opt ReLU ----------------
// hmShift >= 0: write head-major [B,H,Sk,64] with Sk = 1<<hmShift (res/relu unused).
__global__ __launch_bounds__(256) void gemm_k(const float* __restrict__ A,
                                              const float* __restrict__ W,
                                              const float* __restrict__ bias,
                                              const float* __restrict__ res,
                                              float* __restrict__ C,
                                              int M, int N, int K, int relu,
                                              int hmShift) {
  __shared__ float As[16][64];
  __shared__ float Bs[16][64];
  int t = threadIdx.x;
  int tx = t & 15, ty = t >> 4;
  int m0 = blockIdx.y * 64, n0 = blockIdx.x * 64;
  int mA = t >> 2, kA = (t & 3) * 4;
  int kB = t >> 4, nB = (t & 15) * 4;
  const float* Ap = A + (size_t)(m0 + mA) * K + kA;
  const float* Wp = W + (size_t)kB * N + n0 + nB;
  float acc[4][4] = {};
  for (int k0 = 0; k0 < K; k0 += 16) {
    float4 av = *(const float4*)(Ap + k0);
    float4 bv = *(const float4*)(Wp + (size_t)k0 * N);
    As[kA + 0][mA] = av.x; As[kA + 1][mA] = av.y;
    As[kA + 2][mA] = av.z; As[kA + 3][mA] = av.w;
    *(float4*)&Bs[kB][nB] = bv;
    __syncthreads();
#pragma unroll
    for (int k = 0; k < 16; k++) {
      float4 a = *(const float4*)&As[k][ty * 4];
      float4 b = *(const float4*)&Bs[k][tx * 4];
      acc[0][0] += a.x * b.x; acc[0][1] += a.x * b.y; acc[0][2] += a.x * b.z; acc[0][3] += a.x * b.w;
      acc[1][0] += a.y * b.x; acc[1][1] += a.y * b.y; acc[1][2] += a.y * b.z; acc[1][3] += a.y * b.w;
      acc[2][0] += a.z * b.x; acc[2][1] += a.z * b.y; acc[2][2] += a.z * b.z; acc[2][3] += a.z * b.w;
      acc[3][0] += a.w * b.x; acc[3][1] += a.w * b.y; acc[3][2] += a.w * b.z; acc[3][3] += a.w * b.w;
    }
    __syncthreads();
  }
#pragma unroll
  for (int i = 0; i < 4; i++) {
    int m = m0 + ty * 4 + i;
    int n = n0 + tx * 4;
    float4 o;
    o.x = acc[i][0] + bias[n + 0];
    o.y = acc[i][1] + bias[n + 1];
    o.z = acc[i][2] + bias[n + 2];
    o.w = acc[i][3] + bias[n + 3];
    if (hmShift >= 0) {
      int bb = m >> hmShift, ss = m & ((1 << hmShift) - 1);
      int hh = n >> 6, dd = n & 63;
      size_t base = ((((size_t)bb * HH + hh) << hmShift) + ss) * 64 + dd;
      *(float4*)(C + base) = o;
    } else {
      size_t base = (size_t)m * N + n;
      if (res) {
        float4 rv = *(const float4*)(res + base);
        o.x += rv.x; o.y += rv.y; o.z += rv.z; o.w += rv.w;
      }
      if (relu) {
        o.x = fmaxf(o.x, 0.f); o.y = fmaxf(o.y, 0.f);
        o.z = fmaxf(o.z, 0.f); o.w = fmaxf(o.w, 0.f);
      }
      *(float4*)(C + base) = o;
    }
  }
}

// ---------------- fused attention v2: head-major K/V, LDS-tiled ----------------
// grid = (S/16, H, B); block 256. mode: 0=causal+cutoff, 1=src_mask, 2=none.
// qh [B,H,S,64], kh/vh [B,H,SK,64]; ctx written [B,S,D] standard layout.
template <int SK>
__global__ __launch_bounds__(256) void attn2_k(const float* __restrict__ qh,
                                               const float* __restrict__ kh,
                                               const float* __restrict__ vh,
                                               float* __restrict__ ctx, int mode,
                                               const int* __restrict__ rbuf,
                                               const int* __restrict__ smask) {
  __shared__ float qs[16][68];
  __shared__ float kv[64 * 68];       // union: ktT [d][k] (stride 64) / vt [k][d] (stride 68)
  __shared__ float ps[16][SK + 4];
  int qt = blockIdx.x, h = blockIdx.y, b = blockIdx.z;
  int t = threadIdx.x;
  size_t kvbase = ((size_t)b * HH + h) * SK * 64;
  // load Q tile (16 x 64)
  {
    int row = t >> 4, c4 = (t & 15) * 4;
    *(float4*)&qs[row][c4] =
        *(const float4*)(qh + (((size_t)b * HH + h) * SS + qt * 16 + row) * 64 + c4);
  }
  int qi = t >> 4, k4 = (t & 15) * 4;
  int qg = qt * 16 + qi;
  int rcut = (mode == 0) ? rbuf[b] : 0;
  // ---- scores ----
  for (int kt0 = 0; kt0 < SK / 64; kt0++) {
    if (kt0) __syncthreads();
    {
      int k = t >> 2, d0 = (t & 3) * 16;
      const float* kr = kh + kvbase + (size_t)(kt0 * 64 + k) * 64 + d0;
      float4 a0 = *(const float4*)(kr + 0);
      float4 a1 = *(const float4*)(kr + 4);
      float4 a2 = *(const float4*)(kr + 8);
      float4 a3 = *(const float4*)(kr + 12);
      kv[(d0 + 0) * 64 + k] = a0.x; kv[(d0 + 1) * 64 + k] = a0.y;
      kv[(d0 + 2) * 64 + k] = a0.z; kv[(d0 + 3) * 64 + k] = a0.w;
      kv[(d0 + 4) * 64 + k] = a1.x; kv[(d0 + 5) * 64 + k] = a1.y;
      kv[(d0 + 6) * 64 + k] = a1.z; kv[(d0 + 7) * 64 + k] = a1.w;
      kv[(d0 + 8) * 64 + k] = a2.x; kv[(d0 + 9) * 64 + k] = a2.y;
      kv[(d0 + 10) * 64 + k] = a2.z; kv[(d0 + 11) * 64 + k] = a2.w;
      kv[(d0 + 12) * 64 + k] = a3.x; kv[(d0 + 13) * 64 + k] = a3.y;
      kv[(d0 + 14) * 64 + k] = a3.z; kv[(d0 + 15) * 64 + k] = a3.w;
    }
    __syncthreads();
    float a0 = 0.f, a1 = 0.f, a2 = 0.f, a3 = 0.f;
#pragma unroll
    for (int d = 0; d < 64; d++) {
      float qv = qs[qi][d];
      float4 kvv = *(const float4*)&kv[d * 64 + k4];
      a0 += qv * kvv.x; a1 += qv * kvv.y; a2 += qv * kvv.z; a3 += qv * kvv.w;
    }
    int kb0 = kt0 * 64 + k4;
    float4 sc;
    sc.x = a0 * 0.125f; sc.y = a1 * 0.125f; sc.z = a2 * 0.125f; sc.w = a3 * 0.125f;
    if (mode == 0) {
      bool okq = qg < rcut;
      sc.x = (okq && kb0 + 0 <= qg) ? sc.x : -1e9f;
      sc.y = (okq && kb0 + 1 <= qg) ? sc.y : -1e9f;
      sc.z = (okq && kb0 + 2 <= qg) ? sc.z : -1e9f;
      sc.w = (okq && kb0 + 3 <= qg) ? sc.w : -1e9f;
    } else if (mode == 1) {
      const int* sm = smask + b * SRCC + kb0;
      sc.x = sm[0] ? sc.x : -1e9f;
      sc.y = sm[1] ? sc.y : -1e9f;
      sc.z = sm[2] ? sc.z : -1e9f;
      sc.w = sm[3] ? sc.w : -1e9f;
    }
    *(float4*)&ps[qi][kb0] = sc;
  }
  __syncthreads();
  // ---- softmax (row = t>>4, 16 lanes per row) ----
  {
    int row = t >> 4, l16 = t & 15;
    float mx = -3.4e38f;
#pragma unroll
    for (int j = 0; j < SK / 16; j++) mx = fmaxf(mx, ps[row][l16 + 16 * j]);
#pragma unroll
    for (int o = 1; o < 16; o <<= 1) mx = fmaxf(mx, __shfl_xor(mx, o));
    float sum = 0.f;
#pragma unroll
    for (int j = 0; j < SK / 16; j++) {
      int c = l16 + 16 * j;
      float ev = expf(ps[row][c] - mx);
      ps[row][c] = ev;
      sum += ev;
    }
#pragma unroll
    for (int o = 1; o < 16; o <<= 1) sum += __shfl_xor(sum, o);
    float rinv = 1.0f / sum;
#pragma unroll
    for (int j = 0; j < SK / 16; j++) ps[row][l16 + 16 * j] *= rinv;
  }
  // ---- PV ----
  float4 acc = make_float4(0.f, 0.f, 0.f, 0.f);
  int d4 = (t & 15) * 4;
  for (int kt0 = 0; kt0 < SK / 64; kt0++) {
    __syncthreads();
    {
      int k = t >> 2, d0 = (t & 3) * 16;
      const float* vr = vh + kvbase + (size_t)(kt0 * 64 + k) * 64 + d0;
      float4 w0 = *(const float4*)(vr + 0);
      float4 w1 = *(const float4*)(vr + 4);
      float4 w2 = *(const float4*)(vr + 8);
      float4 w3 = *(const float4*)(vr + 12);
      *(float4*)&kv[k * 68 + d0 + 0]  = w0;
      *(float4*)&kv[k * 68 + d0 + 4]  = w1;
      *(float4*)&kv[k * 68 + d0 + 8]  = w2;
      *(float4*)&kv[k * 68 + d0 + 12] = w3;
    }
    __syncthreads();
#pragma unroll
    for (int kk = 0; kk < 64; kk++) {
      float p = ps[qi][kt0 * 64 + kk];
      float4 vv = *(const float4*)&kv[kk * 68 + d4];
      acc.x += p * vv.x; acc.y += p * vv.y; acc.z += p * vv.z; acc.w += p * vv.w;
    }
  }
  *(float4*)(ctx + ((size_t)(b * SS) + qg) * DD + h * 64 + d4) = acc;
}

// ---------------- launch ----------------
extern "C" void kernel_launch(void* const* d_in, const int* in_sizes, int n_in,
                              void* d_out, int out_size, void* d_ws, size_t ws_size,
                              hipStream_t stream) {
  const int*   trg   = (const int*)d_in[0];
  const float* e_out = (const float*)d_in[1];
  const int*   smask = (const int*)d_in[2];
  const float* emb   = (const float*)d_in[3];
  const float* ypar  = (const float*)d_in[4];
  const float* alpha = (const float*)d_in[5];
  const float* Wq = (const float*)d_in[6];
  const float* Wk = (const float*)d_in[7];
  const float* Wv = (const float*)d_in[8];
  const float* Wo = (const float*)d_in[9];
  const float* bq = (const float*)d_in[10];
  const float* bk = (const float*)d_in[11];
  const float* bv = (const float*)d_in[12];
  const float* bo = (const float*)d_in[13];
  const float* W1 = (const float*)d_in[14];
  const float* b1 = (const float*)d_in[15];
  const float* W2 = (const float*)d_in[16];
  const float* b2 = (const float*)d_in[17];
  const float* lna = (const float*)d_in[18];
  const float* lnb = (const float*)d_in[19];
  const float* fa = (const float*)d_in[20];
  const float* fb = (const float*)d_in[21];
  float* out = (float*)d_out;

  float* ws = (float*)d_ws;
  size_t off = 0;
  float* pe = ws + off;  off += (size_t)SS * DD;
  int* rbuf = (int*)(ws + off); off += 64;
  float* x   = ws + off; off += (size_t)BB * SS * DD;
  float* y   = ws + off; off += (size_t)BB * SS * DD;
  float* x2  = ws + off; off += (size_t)BB * SS * DD;
  float* y3  = ws + off; off += (size_t)BB * SS * DD;
  float* qb  = ws + off; off += (size_t)BB * SS * DD;
  float* kb  = ws + off; off += (size_t)BB * SRCC * DD;
  float* vb  = ws + off; off += (size_t)BB * SRCC * DD;
  float* ctx = ws + off; off += (size_t)BB * SS * DD;
  float* mid = ws + off; off += (size_t)BB * SS * DFFF;
  if (ws_size < off * sizeof(float)) return;

  pe_build_k<<<(SS * (DD / 2) + 255) / 256, 256, 0, stream>>>(pe);
  embed_k<<<(BB * SS * (DD / 4) + 255) / 256, 256, 0, stream>>>(trg, emb, pe, alpha, x);
  yinit_k<<<(BB * SS * (DD / 4) + 255) / 256, 256, 0, stream>>>(ypar, y);
  mask_k<<<1, 64, 0, stream>>>(trg, rbuf);

  auto GEMM = [&](const float* A, int M, int K, const float* W, int N,
                  const float* bias, const float* res, float* C, int relu, int hmShift) {
    gemm_k<<<dim3(N / 64, M / 64), 256, 0, stream>>>(A, W, bias, res, C, M, N, K, relu, hmShift);
  };
  const dim3 agrid(SS / 16, HH, BB);

  for (int l = 0; l < NLL; l++) {
    const float* wq[3], *wk[3], *wv[3], *wo[3], *bql[3], *bkl[3], *bvl[3], *bol[3];
    for (int j = 0; j < 3; j++) {
      size_t wOff = ((size_t)l * 3 + j) * DD * DD;
      size_t bOff = ((size_t)l * 3 + j) * DD;
      wq[j] = Wq + wOff; wk[j] = Wk + wOff; wv[j] = Wv + wOff; wo[j] = Wo + wOff;
      bql[j] = bq + bOff; bkl[j] = bk + bOff; bvl[j] = bv + bOff; bol[j] = bo + bOff;
    }
    auto LN = [&](const float* in, int slot, float* o) {
      ln_k<<<BB * SS, 256, 0, stream>>>(in, lna + ((size_t)l * 5 + slot) * DD,
                                        lnb + ((size_t)l * 5 + slot) * DD, o);
    };
    // ---- MHA1: self-attn on x (causal + cutoff mask) ----
    LN(x, 0, x2);
    GEMM(x2, BB * SS, DD, wq[0], DD, bql[0], nullptr, qb, 0, 7);
    GEMM(x2, BB * SS, DD, wk[0], DD, bkl[0], nullptr, kb, 0, 7);
    GEMM(x2, BB * SS, DD, wv[0], DD, bvl[0], nullptr, vb, 0, 7);
    attn2_k<SS><<<agrid, 256, 0, stream>>>(qb, kb, vb, ctx, 0, rbuf, nullptr);
    GEMM(ctx, BB * SS, DD, wo[0], DD, bol[0], x, x, 0, -1);
    // ---- MHA2: y cross-attends e_outputs (src mask) ----
    LN(y, 1, x2);
    GEMM(x2, BB * SS, DD, wq[1], DD, bql[1], nullptr, qb, 0, 7);
    GEMM(e_out, BB * SRCC, DD, wk[1], DD, bkl[1], nullptr, kb, 0, 8);
    GEMM(e_out, BB * SRCC, DD, wv[1], DD, bvl[1], nullptr, vb, 0, 8);
    attn2_k<SRCC><<<agrid, 256, 0, stream>>>(qb, kb, vb, ctx, 1, nullptr, smask);
    GEMM(ctx, BB * SS, DD, wo[1], DD, bol[1], y, y, 0, -1);
    // ---- MHA3: x cross-attends ln(y) (no mask) ----
    LN(x, 2, x2);
    LN(y, 3, y3);
    GEMM(x2, BB * SS, DD, wq[2], DD, bql[2], nullptr, qb, 0, 7);
    GEMM(y3, BB * SS, DD, wk[2], DD, bkl[2], nullptr, kb, 0, 7);
    GEMM(y3, BB * SS, DD, wv[2], DD, bvl[2], nullptr, vb, 0, 7);
    attn2_k<SS><<<agrid, 256, 0, stream>>>(qb, kb, vb, ctx, 2, nullptr, nullptr);
    GEMM(ctx, BB * SS, DD, wo[2], DD, bol[2], x, x, 0, -1);
    // ---- FFN ----
    LN(x, 4, x2);
    GEMM(x2, BB * SS, DD, W1 + (size_t)l * DD * DFFF, DFFF, b1 + (size_t)l * DFFF,
         nullptr, mid, 1, -1);
    GEMM(mid, BB * SS, DFFF, W2 + (size_t)l * DFFF * DD, DD, b2 + (size_t)l * DD, x, x, 0, -1);
  }
  ln_k<<<BB * SS, 256, 0, stream>>>(x, fa, fb, out);
}

// Round 3
// 2724.794 us; speedup vs baseline: 6.6799x; 2.9075x over previous
//
#include <hip/hip_runtime.h>

#define BB 16
#define SS 128
#define DD 768
#define HH 12
#define DKK 64
#define DFFF 3072
#define NLL 6
#define SRCC 256

typedef short bf16x8 __attribute__((ext_vector_type(8)));   // 8 bf16 as i16 (guide-verified)
typedef float f32x4 __attribute__((ext_vector_type(4)));
typedef unsigned short us8 __attribute__((ext_vector_type(8)));
typedef unsigned short us4 __attribute__((ext_vector_type(4)));

__device__ __forceinline__ unsigned short f2bf(float f) {
  unsigned int u = __builtin_bit_cast(unsigned int, f);
  u = (u + 0x7fff + ((u >> 16) & 1)) >> 16;
  return (unsigned short)u;
}

#define GLOADLDS16(gp, lp)                                              \
  __builtin_amdgcn_global_load_lds(                                     \
      (const __attribute__((address_space(1))) void*)(gp),              \
      (__attribute__((address_space(3))) void*)(lp), 16, 0, 0)

// ---------------- positional encoding table ----------------
__global__ void pe_build_k(float* __restrict__ pe) {
  int idx = blockIdx.x * blockDim.x + threadIdx.x;
  if (idx >= SS * (DD / 2)) return;
  int s = idx / (DD / 2);
  int i = idx - s * (DD / 2);
  float div = expf((float)(2 * i) * (-logf(10000.0f) / (float)DD));
  float ang = (float)s * div;
  pe[s * DD + 2 * i]     = sinf(ang);
  pe[s * DD + 2 * i + 1] = cosf(ang);
}

// ---------------- x = emb[trg] + alpha * pe ----------------
__global__ void embed_k(const int* __restrict__ trg, const float* __restrict__ emb,
                        const float* __restrict__ pe, const float* __restrict__ alpha,
                        float* __restrict__ x) {
  int idx = blockIdx.x * blockDim.x + threadIdx.x;
  int c = idx % (DD / 4);
  int r = idx / (DD / 4);
  if (r >= BB * SS) return;
  int s = r % SS;
  float al = alpha[0];
  float4 e = *(const float4*)(emb + (size_t)trg[r] * DD + c * 4);
  float4 p = *(const float4*)(pe + (size_t)s * DD + c * 4);
  float4 o;
  o.x = e.x + al * p.x; o.y = e.y + al * p.y;
  o.z = e.z + al * p.z; o.w = e.w + al * p.w;
  *(float4*)(x + (size_t)r * DD + c * 4) = o;
}

// ---------------- y = broadcast(y_param) ----------------
__global__ void yinit_k(const float* __restrict__ yp, float* __restrict__ y) {
  int idx = blockIdx.x * blockDim.x + threadIdx.x;
  int c = idx % (DD / 4);
  int r = idx / (DD / 4);
  if (r >= BB * SS) return;
  int s = r % SS;
  *(float4*)(y + (size_t)r * DD + c * 4) = *(const float4*)(yp + (size_t)s * DD + c * 4);
}

// ---------------- combined mask cutoff r[b] ----------------
__global__ void mask_k(const int* __restrict__ trg, int* __restrict__ rbuf) {
  if (threadIdx.x != 0 || blockIdx.x != 0) return;
  int cmin = 0x7fffffff;
  int cm[BB];
  for (int b = 0; b < BB; b++) {
    int start = 0;
    for (int s = 0; s < SS; s++) {
      if (trg[b * SS + s] == 0) { start = s; break; }
    }
    int c = (start == 0) ? (SS + 1) : start;
    cmin = min(cmin, c);
    cm[b] = cmin;
  }
  for (int b = 0; b < BB; b++) rbuf[b] = cm[min(b, BB - 2)];
}

// ---------------- LayerNorm f32-out (final) ----------------
__global__ __launch_bounds__(256) void ln_k(const float* __restrict__ x,
                                            const float* __restrict__ ga,
                                            const float* __restrict__ gb,
                                            float* __restrict__ out) {
  __shared__ float sm[8];
  int row = blockIdx.x;
  int t = threadIdx.x;
  const float* xr = x + (size_t)row * DD;
  float v0 = xr[t], v1 = xr[t + 256], v2 = xr[t + 512];
  float s = v0 + v1 + v2;
#pragma unroll
  for (int o = 32; o > 0; o >>= 1) s += __shfl_down(s, o);
  if ((t & 63) == 0) sm[t >> 6] = s;
  __syncthreads();
  float mean = (sm[0] + sm[1] + sm[2] + sm[3]) * (1.0f / (float)DD);
  float d0 = v0 - mean, d1 = v1 - mean, d2 = v2 - mean;
  float q = d0 * d0 + d1 * d1 + d2 * d2;
#pragma unroll
  for (int o = 32; o > 0; o >>= 1) q += __shfl_down(q, o);
  if ((t & 63) == 0) sm[4 + (t >> 6)] = q;
  __syncthreads();
  float var = (sm[4] + sm[5] + sm[6] + sm[7]) * (1.0f / (float)DD);
  float inv = 1.0f / sqrtf(var + 1e-6f);
  float* orow = out + (size_t)row * DD;
  orow[t]       = ga[t] * d0 * inv + gb[t];
  orow[t + 256] = ga[t + 256] * d1 * inv + gb[t + 256];
  orow[t + 512] = ga[t + 512] * d2 * inv + gb[t + 512];
}

// ---------------- LayerNorm bf16-out (GEMM inputs) ----------------
__global__ __launch_bounds__(256) void lnb_k(const float* __restrict__ x,
                                             const float* __restrict__ ga,
                                             const float* __restrict__ gb,
                                             unsigned short* __restrict__ out) {
  __shared__ float sm[8];
  int row = blockIdx.x;
  int t = threadIdx.x;
  const float* xr = x + (size_t)row * DD;
  float v0 = xr[t], v1 = xr[t + 256], v2 = xr[t + 512];
  float s = v0 + v1 + v2;
#pragma unroll
  for (int o = 32; o > 0; o >>= 1) s += __shfl_down(s, o);
  if ((t & 63) == 0) sm[t >> 6] = s;
  __syncthreads();
  float mean = (sm[0] + sm[1] + sm[2] + sm[3]) * (1.0f / (float)DD);
  float d0 = v0 - mean, d1 = v1 - mean, d2 = v2 - mean;
  float q = d0 * d0 + d1 * d1 + d2 * d2;
#pragma unroll
  for (int o = 32; o > 0; o >>= 1) q += __shfl_down(q, o);
  if ((t & 63) == 0) sm[4 + (t >> 6)] = q;
  __syncthreads();
  float var = (sm[4] + sm[5] + sm[6] + sm[7]) * (1.0f / (float)DD);
  float inv = 1.0f / sqrtf(var + 1e-6f);
  unsigned short* orow = out + (size_t)row * DD;
  orow[t]       = f2bf(ga[t] * d0 * inv + gb[t]);
  orow[t + 256] = f2bf(ga[t + 256] * d1 * inv + gb[t + 256]);
  orow[t + 512] = f2bf(ga[t + 512] * d2 * inv + gb[t + 512]);
}

// ---------------- weight transpose+convert: f32 [K][N] -> bf16 [N][K] ----------------
__global__ __launch_bounds__(256) void wt_k(const float* __restrict__ src,
                                            unsigned short* __restrict__ dst,
                                            int K, int N) {
  __shared__ float tl[64][65];
  int t = threadIdx.x;
  int n0 = blockIdx.x * 64, k0 = blockIdx.y * 64;
  const float* s = src + (size_t)blockIdx.z * K * N;
  unsigned short* d = dst + (size_t)blockIdx.z * K * N;
  int r = t >> 2, cq = (t & 3) * 16;
#pragma unroll
  for (int i = 0; i < 4; i++) {
    float4 v = *(const float4*)(s + (size_t)(k0 + r) * N + n0 + cq + i * 4);
    tl[r][cq + i * 4 + 0] = v.x;
    tl[r][cq + i * 4 + 1] = v.y;
    tl[r][cq + i * 4 + 2] = v.z;
    tl[r][cq + i * 4 + 3] = v.w;
  }
  __syncthreads();
  int nn = t >> 2, kq = (t & 3) * 16;
#pragma unroll
  for (int half = 0; half < 2; half++) {
    us8 o;
#pragma unroll
    for (int j = 0; j < 8; j++) o[j] = f2bf(tl[kq + half * 8 + j][nn]);
    *(us8*)(d + (size_t)(n0 + nn) * K + k0 + kq + half * 8) = o;
  }
}

// ---------------- elementwise f32 -> bf16 ----------------
__global__ void cvt_k(const float* __restrict__ s, unsigned short* __restrict__ d, int n8) {
  int i = blockIdx.x * blockDim.x + threadIdx.x;
  if (i >= n8) return;
  float4 a = *(const float4*)(s + (size_t)i * 8);
  float4 b = *(const float4*)(s + (size_t)i * 8 + 4);
  us8 o;
  o[0] = f2bf(a.x); o[1] = f2bf(a.y); o[2] = f2bf(a.z); o[3] = f2bf(a.w);
  o[4] = f2bf(b.x); o[5] = f2bf(b.y); o[6] = f2bf(b.z); o[7] = f2bf(b.w);
  *(us8*)(d + (size_t)i * 8) = o;
}

// ---------------- bf16 MFMA GEMM ----------------
// A bf16 [M][K]; Bt bf16 [N][K]; 128x64 tile, BK=32, 256 thr, 4 waves 2x2.
// hmShift>=0: head-major f32 [B,H,1<<hmShift,64] out. flags: 1=relu, 2=bf16 out.
__global__ __launch_bounds__(256) void mgemm_k(const unsigned short* __restrict__ A,
                                               const unsigned short* __restrict__ Bt,
                                               const float* __restrict__ bias,
                                               const float* __restrict__ res,
                                               void* __restrict__ C,
                                               int M, int N, int K,
                                               int flags, int hmShift) {
  __shared__ unsigned short As[128 * 32];
  __shared__ unsigned short Bs[64 * 32];
  int t = threadIdx.x;
  int wave = t >> 6, lane = t & 63;
  int m0 = blockIdx.y * 128, n0 = blockIdx.x * 64;
  int wm = wave >> 1, wn = wave & 1;
  f32x4 acc[4][2] = {};
  int aRow = t >> 2, aC8 = (t & 3) * 8;
  const unsigned short* Ab = A + (size_t)m0 * K + aC8;
  const unsigned short* Bb = Bt + (size_t)n0 * K + aC8;
  unsigned short* As0 = As + wave * 512;
  unsigned short* As1 = As + 2048 + wave * 512;
  unsigned short* Bs0 = Bs + wave * 512;
  // fragment LDS offsets (ushort units)
  int aOff0 = (wm * 64 + (lane & 15)) * 32 + (lane >> 4) * 8;
  int bOff0 = (wn * 32 + (lane & 15)) * 32 + (lane >> 4) * 8;
  for (int k0 = 0; k0 < K; k0 += 32) {
    GLOADLDS16(Ab + (size_t)aRow * K + k0, As0);
    GLOADLDS16(Ab + (size_t)(64 + aRow) * K + k0, As1);
    GLOADLDS16(Bb + (size_t)aRow * K + k0, Bs0);
    __syncthreads();
    bf16x8 aF[4], bF[2];
#pragma unroll
    for (int fm = 0; fm < 4; fm++)
      aF[fm] = *(const bf16x8*)(As + aOff0 + fm * 16 * 32);
#pragma unroll
    for (int fn = 0; fn < 2; fn++)
      bF[fn] = *(const bf16x8*)(Bs + bOff0 + fn * 16 * 32);
#pragma unroll
    for (int fm = 0; fm < 4; fm++)
#pragma unroll
      for (int fn = 0; fn < 2; fn++)
        acc[fm][fn] = __builtin_amdgcn_mfma_f32_16x16x32_bf16(aF[fm], bF[fn], acc[fm][fn], 0, 0, 0);
    __syncthreads();
  }
  int lcol = lane & 15, lrow4 = (lane >> 4) * 4;
#pragma unroll
  for (int fm = 0; fm < 4; fm++) {
#pragma unroll
    for (int fn = 0; fn < 2; fn++) {
      int col = n0 + wn * 32 + fn * 16 + lcol;
      float bv = bias[col];
#pragma unroll
      for (int r = 0; r < 4; r++) {
        int row = m0 + wm * 64 + fm * 16 + lrow4 + r;
        float v = acc[fm][fn][r] + bv;
        if (hmShift >= 0) {
          int bb = row >> hmShift, ssi = row & ((1 << hmShift) - 1);
          int hh = col >> 6, dd = col & 63;
          size_t idx = ((((size_t)bb * HH + hh) << hmShift) + ssi) * 64 + dd;
          ((float*)C)[idx] = v;
        } else {
          size_t idx = (size_t)row * N + col;
          if (res) v += res[idx];
          if (flags & 1) v = fmaxf(v, 0.f);
          if (flags & 2) ((unsigned short*)C)[idx] = f2bf(v);
          else ((float*)C)[idx] = v;
        }
      }
    }
  }
}

// ---------------- fused attention: head-major K/V, LDS-tiled, bf16 ctx out ----------------
template <int SK>
__global__ __launch_bounds__(256) void attn2_k(const float* __restrict__ qh,
                                               const float* __restrict__ kh,
                                               const float* __restrict__ vh,
                                               unsigned short* __restrict__ ctxb, int mode,
                                               const int* __restrict__ rbuf,
                                               const int* __restrict__ smask) {
  __shared__ float qs[16][68];
  __shared__ float kv[64 * 68];
  __shared__ float ps[16][SK + 4];
  int qt = blockIdx.x, h = blockIdx.y, b = blockIdx.z;
  int t = threadIdx.x;
  size_t kvbase = ((size_t)b * HH + h) * SK * 64;
  {
    int row = t >> 4, c4 = (t & 15) * 4;
    *(float4*)&qs[row][c4] =
        *(const float4*)(qh + (((size_t)b * HH + h) * SS + qt * 16 + row) * 64 + c4);
  }
  int qi = t >> 4, k4 = (t & 15) * 4;
  int qg = qt * 16 + qi;
  int rcut = (mode == 0) ? rbuf[b] : 0;
  for (int kt0 = 0; kt0 < SK / 64; kt0++) {
    if (kt0) __syncthreads();
    {
      int k = t >> 2, d0 = (t & 3) * 16;
      const float* kr = kh + kvbase + (size_t)(kt0 * 64 + k) * 64 + d0;
      float4 a0 = *(const float4*)(kr + 0);
      float4 a1 = *(const float4*)(kr + 4);
      float4 a2 = *(const float4*)(kr + 8);
      float4 a3 = *(const float4*)(kr + 12);
      kv[(d0 + 0) * 64 + k] = a0.x; kv[(d0 + 1) * 64 + k] = a0.y;
      kv[(d0 + 2) * 64 + k] = a0.z; kv[(d0 + 3) * 64 + k] = a0.w;
      kv[(d0 + 4) * 64 + k] = a1.x; kv[(d0 + 5) * 64 + k] = a1.y;
      kv[(d0 + 6) * 64 + k] = a1.z; kv[(d0 + 7) * 64 + k] = a1.w;
      kv[(d0 + 8) * 64 + k] = a2.x; kv[(d0 + 9) * 64 + k] = a2.y;
      kv[(d0 + 10) * 64 + k] = a2.z; kv[(d0 + 11) * 64 + k] = a2.w;
      kv[(d0 + 12) * 64 + k] = a3.x; kv[(d0 + 13) * 64 + k] = a3.y;
      kv[(d0 + 14) * 64 + k] = a3.z; kv[(d0 + 15) * 64 + k] = a3.w;
    }
    __syncthreads();
    float a0 = 0.f, a1 = 0.f, a2 = 0.f, a3 = 0.f;
#pragma unroll
    for (int d = 0; d < 64; d++) {
      float qv = qs[qi][d];
      float4 kvv = *(const float4*)&kv[d * 64 + k4];
      a0 += qv * kvv.x; a1 += qv * kvv.y; a2 += qv * kvv.z; a3 += qv * kvv.w;
    }
    int kb0 = kt0 * 64 + k4;
    float4 sc;
    sc.x = a0 * 0.125f; sc.y = a1 * 0.125f; sc.z = a2 * 0.125f; sc.w = a3 * 0.125f;
    if (mode == 0) {
      bool okq = qg < rcut;
      sc.x = (okq && kb0 + 0 <= qg) ? sc.x : -1e9f;
      sc.y = (okq && kb0 + 1 <= qg) ? sc.y : -1e9f;
      sc.z = (okq && kb0 + 2 <= qg) ? sc.z : -1e9f;
      sc.w = (okq && kb0 + 3 <= qg) ? sc.w : -1e9f;
    } else if (mode == 1) {
      const int* sm = smask + b * SRCC + kb0;
      sc.x = sm[0] ? sc.x : -1e9f;
      sc.y = sm[1] ? sc.y : -1e9f;
      sc.z = sm[2] ? sc.z : -1e9f;
      sc.w = sm[3] ? sc.w : -1e9f;
    }
    *(float4*)&ps[qi][kb0] = sc;
  }
  __syncthreads();
  {
    int row = t >> 4, l16 = t & 15;
    float mx = -3.4e38f;
#pragma unroll
    for (int j = 0; j < SK / 16; j++) mx = fmaxf(mx, ps[row][l16 + 16 * j]);
#pragma unroll
    for (int o = 1; o < 16; o <<= 1) mx = fmaxf(mx, __shfl_xor(mx, o));
    float sum = 0.f;
#pragma unroll
    for (int j = 0; j < SK / 16; j++) {
      int c = l16 + 16 * j;
      float ev = expf(ps[row][c] - mx);
      ps[row][c] = ev;
      sum += ev;
    }
#pragma unroll
    for (int o = 1; o < 16; o <<= 1) sum += __shfl_xor(sum, o);
    float rinv = 1.0f / sum;
#pragma unroll
    for (int j = 0; j < SK / 16; j++) ps[row][l16 + 16 * j] *= rinv;
  }
  float4 acc = make_float4(0.f, 0.f, 0.f, 0.f);
  int d4 = (t & 15) * 4;
  for (int kt0 = 0; kt0 < SK / 64; kt0++) {
    __syncthreads();
    {
      int k = t >> 2, d0 = (t & 3) * 16;
      const float* vr = vh + kvbase + (size_t)(kt0 * 64 + k) * 64 + d0;
      float4 w0 = *(const float4*)(vr + 0);
      float4 w1 = *(const float4*)(vr + 4);
      float4 w2 = *(const float4*)(vr + 8);
      float4 w3 = *(const float4*)(vr + 12);
      *(float4*)&kv[k * 68 + d0 + 0]  = w0;
      *(float4*)&kv[k * 68 + d0 + 4]  = w1;
      *(float4*)&kv[k * 68 + d0 + 8]  = w2;
      *(float4*)&kv[k * 68 + d0 + 12] = w3;
    }
    __syncthreads();
#pragma unroll
    for (int kk = 0; kk < 64; kk++) {
      float p = ps[qi][kt0 * 64 + kk];
      float4 vv = *(const float4*)&kv[kk * 68 + d4];
      acc.x += p * vv.x; acc.y += p * vv.y; acc.z += p * vv.z; acc.w += p * vv.w;
    }
  }
  us4 o;
  o[0] = f2bf(acc.x); o[1] = f2bf(acc.y); o[2] = f2bf(acc.z); o[3] = f2bf(acc.w);
  *(us4*)(ctxb + ((size_t)(b * SS) + qg) * DD + h * 64 + d4) = o;
}

// ---------------- launch ----------------
extern "C" void kernel_launch(void* const* d_in, const int* in_sizes, int n_in,
                              void* d_out, int out_size, void* d_ws, size_t ws_size,
                              hipStream_t stream) {
  const int*   trg   = (const int*)d_in[0];
  const float* e_out = (const float*)d_in[1];
  const int*   smask = (const int*)d_in[2];
  const float* emb   = (const float*)d_in[3];
  const float* ypar  = (const float*)d_in[4];
  const float* alpha = (const float*)d_in[5];
  const float* Wq = (const float*)d_in[6];
  const float* Wk = (const float*)d_in[7];
  const float* Wv = (const float*)d_in[8];
  const float* Wo = (const float*)d_in[9];
  const float* bq = (const float*)d_in[10];
  const float* bk = (const float*)d_in[11];
  const float* bv = (const float*)d_in[12];
  const float* bo = (const float*)d_in[13];
  const float* W1 = (const float*)d_in[14];
  const float* b1 = (const float*)d_in[15];
  const float* W2 = (const float*)d_in[16];
  const float* b2 = (const float*)d_in[17];
  const float* lna = (const float*)d_in[18];
  const float* lnb = (const float*)d_in[19];
  const float* fa = (const float*)d_in[20];
  const float* fb = (const float*)d_in[21];
  float* out = (float*)d_out;

  float* ws = (float*)d_ws;
  size_t off = 0;
  auto alloc = [&](size_t n) { float* p = ws + off; off += n; return p; };
  float* pe  = alloc((size_t)SS * DD);
  int* rbuf  = (int*)alloc(64);
  float* x   = alloc((size_t)BB * SS * DD);
  float* y   = alloc((size_t)BB * SS * DD);
  float* qb  = alloc((size_t)BB * SS * DD);
  float* kb  = alloc((size_t)BB * SRCC * DD);
  float* vb  = alloc((size_t)BB * SRCC * DD);
  unsigned short* x2b  = (unsigned short*)alloc((size_t)BB * SS * DD / 2);
  unsigned short* y3b  = (unsigned short*)alloc((size_t)BB * SS * DD / 2);
  unsigned short* ctxb = (unsigned short*)alloc((size_t)BB * SS * DD / 2);
  unsigned short* midb = (unsigned short*)alloc((size_t)BB * SS * DFFF / 2);
  unsigned short* eob  = (unsigned short*)alloc((size_t)BB * SRCC * DD / 2);
  unsigned short* wqt  = (unsigned short*)alloc((size_t)3 * DD * DD / 2);
  unsigned short* wkt  = (unsigned short*)alloc((size_t)3 * DD * DD / 2);
  unsigned short* wvt  = (unsigned short*)alloc((size_t)3 * DD * DD / 2);
  unsigned short* wot  = (unsigned short*)alloc((size_t)3 * DD * DD / 2);
  unsigned short* w1t  = (unsigned short*)alloc((size_t)DD * DFFF / 2);
  unsigned short* w2t  = (unsigned short*)alloc((size_t)DFFF * DD / 2);
  if (ws_size < off * sizeof(float)) return;

  pe_build_k<<<(SS * (DD / 2) + 255) / 256, 256, 0, stream>>>(pe);
  embed_k<<<(BB * SS * (DD / 4) + 255) / 256, 256, 0, stream>>>(trg, emb, pe, alpha, x);
  yinit_k<<<(BB * SS * (DD / 4) + 255) / 256, 256, 0, stream>>>(ypar, y);
  mask_k<<<1, 64, 0, stream>>>(trg, rbuf);
  cvt_k<<<(BB * SRCC * DD / 8 + 255) / 256, 256, 0, stream>>>(e_out, eob, BB * SRCC * DD / 8);

  auto MGEMM = [&](const unsigned short* A, int M, int K, const unsigned short* Bt, int N,
                   const float* bias, const float* res, void* C, int flags, int hmShift) {
    mgemm_k<<<dim3(N / 64, M / 128), 256, 0, stream>>>(A, Bt, bias, res, C, M, N, K, flags, hmShift);
  };
  const dim3 agrid(SS / 16, HH, BB);

  for (int l = 0; l < NLL; l++) {
    // per-layer weight transpose+convert to bf16 [N][K]
    wt_k<<<dim3(DD / 64, DD / 64, 3), 256, 0, stream>>>(Wq + (size_t)l * 3 * DD * DD, wqt, DD, DD);
    wt_k<<<dim3(DD / 64, DD / 64, 3), 256, 0, stream>>>(Wk + (size_t)l * 3 * DD * DD, wkt, DD, DD);
    wt_k<<<dim3(DD / 64, DD / 64, 3), 256, 0, stream>>>(Wv + (size_t)l * 3 * DD * DD, wvt, DD, DD);
    wt_k<<<dim3(DD / 64, DD / 64, 3), 256, 0, stream>>>(Wo + (size_t)l * 3 * DD * DD, wot, DD, DD);
    wt_k<<<dim3(DFFF / 64, DD / 64, 1), 256, 0, stream>>>(W1 + (size_t)l * DD * DFFF, w1t, DD, DFFF);
    wt_k<<<dim3(DD / 64, DFFF / 64, 1), 256, 0, stream>>>(W2 + (size_t)l * DFFF * DD, w2t, DFFF, DD);

    const float *bql[3], *bkl[3], *bvl[3], *bol[3];
    for (int j = 0; j < 3; j++) {
      size_t bOff = ((size_t)l * 3 + j) * DD;
      bql[j] = bq + bOff; bkl[j] = bk + bOff; bvl[j] = bv + bOff; bol[j] = bo + bOff;
    }
    auto LNB = [&](const float* in, int slot, unsigned short* o) {
      lnb_k<<<BB * SS, 256, 0, stream>>>(in, lna + ((size_t)l * 5 + slot) * DD,
                                         lnb + ((size_t)l * 5 + slot) * DD, o);
    };
    const size_t wstep = (size_t)DD * DD;
    // ---- MHA1: self-attn on x (causal + cutoff) ----
    LNB(x, 0, x2b);
    MGEMM(x2b, BB * SS, DD, wqt + 0 * wstep, DD, bql[0], nullptr, qb, 0, 7);
    MGEMM(x2b, BB * SS, DD, wkt + 0 * wstep, DD, bkl[0], nullptr, kb, 0, 7);
    MGEMM(x2b, BB * SS, DD, wvt + 0 * wstep, DD, bvl[0], nullptr, vb, 0, 7);
    attn2_k<SS><<<agrid, 256, 0, stream>>>(qb, kb, vb, ctxb, 0, rbuf, nullptr);
    MGEMM(ctxb, BB * SS, DD, wot + 0 * wstep, DD, bol[0], x, x, 0, -1);
    // ---- MHA2: y cross-attends e_outputs (src mask) ----
    LNB(y, 1, x2b);
    MGEMM(x2b, BB * SS, DD, wqt + 1 * wstep, DD, bql[1], nullptr, qb, 0, 7);
    MGEMM(eob, BB * SRCC, DD, wkt + 1 * wstep, DD, bkl[1], nullptr, kb, 0, 8);
    MGEMM(eob, BB * SRCC, DD, wvt + 1 * wstep, DD, bvl[1], nullptr, vb, 0, 8);
    attn2_k<SRCC><<<agrid, 256, 0, stream>>>(qb, kb, vb, ctxb, 1, nullptr, smask);
    MGEMM(ctxb, BB * SS, DD, wot + 1 * wstep, DD, bol[1], y, y, 0, -1);
    // ---- MHA3: x cross-attends ln(y) ----
    LNB(x, 2, x2b);
    LNB(y, 3, y3b);
    MGEMM(x2b, BB * SS, DD, wqt + 2 * wstep, DD, bql[2], nullptr, qb, 0, 7);
    MGEMM(y3b, BB * SS, DD, wkt + 2 * wstep, DD, bkl[2], nullptr, kb, 0, 7);
    MGEMM(y3b, BB * SS, DD, wvt + 2 * wstep, DD, bvl[2], nullptr, vb, 0, 7);
    attn2_k<SS><<<agrid, 256, 0, stream>>>(qb, kb, vb, ctxb, 2, nullptr, nullptr);
    MGEMM(ctxb, BB * SS, DD, wot + 2 * wstep, DD, bol[2], x, x, 0, -1);
    // ---- FFN ----
    LNB(x, 4, x2b);
    MGEMM(x2b, BB * SS, DD, w1t, DFFF, b1 + (size_t)l * DFFF, nullptr, midb, 3, -1);
    MGEMM(midb, BB * SS, DFFF, w2t, DD, b2 + (size_t)l * DD, x, x, 0, -1);
  }
  ln_k<<<BB * SS, 256, 0, stream>>>(x, fa, fb, out);
}

// Round 4
// 2070.490 us; speedup vs baseline: 8.7908x; 1.3160x over previous
//
#include <hip/hip_runtime.h>

#define BB 16
#define SS 128
#define DD 768
#define HH 12
#define DKK 64
#define DFFF 3072
#define NLL 6
#define SRCC 256

typedef short bf16x8 __attribute__((ext_vector_type(8)));
typedef float f32x4 __attribute__((ext_vector_type(4)));
typedef unsigned short us8 __attribute__((ext_vector_type(8)));
typedef unsigned short us4 __attribute__((ext_vector_type(4)));

__device__ __forceinline__ unsigned short f2bf(float f) {
  unsigned int u = __builtin_bit_cast(unsigned int, f);
  u = (u + 0x7fff + ((u >> 16) & 1)) >> 16;
  return (unsigned short)u;
}

#define GLOADLDS16(gp, lp)                                              \
  __builtin_amdgcn_global_load_lds(                                     \
      (const __attribute__((address_space(1))) void*)(gp),              \
      (__attribute__((address_space(3))) void*)(lp), 16, 0, 0)

// ---------------- positional encoding table ----------------
__global__ void pe_build_k(float* __restrict__ pe) {
  int idx = blockIdx.x * blockDim.x + threadIdx.x;
  if (idx >= SS * (DD / 2)) return;
  int s = idx / (DD / 2);
  int i = idx - s * (DD / 2);
  float div = expf((float)(2 * i) * (-logf(10000.0f) / (float)DD));
  float ang = (float)s * div;
  pe[s * DD + 2 * i]     = sinf(ang);
  pe[s * DD + 2 * i + 1] = cosf(ang);
}

// ---------------- x = emb[trg] + alpha * pe ----------------
__global__ void embed_k(const int* __restrict__ trg, const float* __restrict__ emb,
                        const float* __restrict__ pe, const float* __restrict__ alpha,
                        float* __restrict__ x) {
  int idx = blockIdx.x * blockDim.x + threadIdx.x;
  int c = idx % (DD / 4);
  int r = idx / (DD / 4);
  if (r >= BB * SS) return;
  int s = r % SS;
  float al = alpha[0];
  float4 e = *(const float4*)(emb + (size_t)trg[r] * DD + c * 4);
  float4 p = *(const float4*)(pe + (size_t)s * DD + c * 4);
  float4 o;
  o.x = e.x + al * p.x; o.y = e.y + al * p.y;
  o.z = e.z + al * p.z; o.w = e.w + al * p.w;
  *(float4*)(x + (size_t)r * DD + c * 4) = o;
}

// ---------------- y = broadcast(y_param) ----------------
__global__ void yinit_k(const float* __restrict__ yp, float* __restrict__ y) {
  int idx = blockIdx.x * blockDim.x + threadIdx.x;
  int c = idx % (DD / 4);
  int r = idx / (DD / 4);
  if (r >= BB * SS) return;
  int s = r % SS;
  *(float4*)(y + (size_t)r * DD + c * 4) = *(const float4*)(yp + (size_t)s * DD + c * 4);
}

// ---------------- combined mask cutoff r[b] (parallel) ----------------
__global__ void mask2_k(const int* __restrict__ trg, int* __restrict__ rbuf) {
  __shared__ int first[BB];
  int t = threadIdx.x;
  if (t < BB) first[t] = 0x7fffffff;
  __syncthreads();
  int b = t >> 4, p0 = (t & 15) * 8;
  int loc = 0x7fffffff;
#pragma unroll
  for (int i = 0; i < 8; i++) {
    if (trg[b * SS + p0 + i] == 0) { loc = p0 + i; break; }
  }
  atomicMin(&first[b], loc);
  __syncthreads();
  if (t == 0) {
    int cmin = 0x7fffffff;
    int cm[BB];
    for (int bb = 0; bb < BB; bb++) {
      int start = (first[bb] == 0x7fffffff) ? 0 : first[bb];
      int c = (start == 0) ? (SS + 1) : start;
      cmin = min(cmin, c);
      cm[bb] = cmin;
    }
    for (int bb = 0; bb < BB; bb++) rbuf[bb] = cm[min(bb, BB - 2)];
  }
}

// ---------------- LayerNorm f32-out (final) ----------------
__global__ __launch_bounds__(256) void ln_k(const float* __restrict__ x,
                                            const float* __restrict__ ga,
                                            const float* __restrict__ gb,
                                            float* __restrict__ out) {
  __shared__ float sm[8];
  int row = blockIdx.x;
  int t = threadIdx.x;
  const float* xr = x + (size_t)row * DD;
  float v0 = xr[t], v1 = xr[t + 256], v2 = xr[t + 512];
  float s = v0 + v1 + v2;
#pragma unroll
  for (int o = 32; o > 0; o >>= 1) s += __shfl_down(s, o);
  if ((t & 63) == 0) sm[t >> 6] = s;
  __syncthreads();
  float mean = (sm[0] + sm[1] + sm[2] + sm[3]) * (1.0f / (float)DD);
  float d0 = v0 - mean, d1 = v1 - mean, d2 = v2 - mean;
  float q = d0 * d0 + d1 * d1 + d2 * d2;
#pragma unroll
  for (int o = 32; o > 0; o >>= 1) q += __shfl_down(q, o);
  if ((t & 63) == 0) sm[4 + (t >> 6)] = q;
  __syncthreads();
  float var = (sm[4] + sm[5] + sm[6] + sm[7]) * (1.0f / (float)DD);
  float inv = 1.0f / sqrtf(var + 1e-6f);
  float* orow = out + (size_t)row * DD;
  orow[t]       = ga[t] * d0 * inv + gb[t];
  orow[t + 256] = ga[t + 256] * d1 * inv + gb[t + 256];
  orow[t + 512] = ga[t + 512] * d2 * inv + gb[t + 512];
}

// ---------------- LayerNorm bf16-out ----------------
__global__ __launch_bounds__(256) void lnb_k(const float* __restrict__ x,
                                             const float* __restrict__ ga,
                                             const float* __restrict__ gb,
                                             unsigned short* __restrict__ out) {
  __shared__ float sm[8];
  int row = blockIdx.x;
  int t = threadIdx.x;
  const float* xr = x + (size_t)row * DD;
  float v0 = xr[t], v1 = xr[t + 256], v2 = xr[t + 512];
  float s = v0 + v1 + v2;
#pragma unroll
  for (int o = 32; o > 0; o >>= 1) s += __shfl_down(s, o);
  if ((t & 63) == 0) sm[t >> 6] = s;
  __syncthreads();
  float mean = (sm[0] + sm[1] + sm[2] + sm[3]) * (1.0f / (float)DD);
  float d0 = v0 - mean, d1 = v1 - mean, d2 = v2 - mean;
  float q = d0 * d0 + d1 * d1 + d2 * d2;
#pragma unroll
  for (int o = 32; o > 0; o >>= 1) q += __shfl_down(q, o);
  if ((t & 63) == 0) sm[4 + (t >> 6)] = q;
  __syncthreads();
  float var = (sm[4] + sm[5] + sm[6] + sm[7]) * (1.0f / (float)DD);
  float inv = 1.0f / sqrtf(var + 1e-6f);
  unsigned short* orow = out + (size_t)row * DD;
  orow[t]       = f2bf(ga[t] * d0 * inv + gb[t]);
  orow[t + 256] = f2bf(ga[t + 256] * d1 * inv + gb[t + 256]);
  orow[t + 512] = f2bf(ga[t + 512] * d2 * inv + gb[t + 512]);
}

// ---------------- weight transpose: f32 [K][N] -> bf16 [N][K], z strided K*N ----------------
__global__ __launch_bounds__(256) void wt_k(const float* __restrict__ src,
                                            unsigned short* __restrict__ dst,
                                            int K, int N) {
  __shared__ float tl[64][65];
  int t = threadIdx.x;
  int n0 = blockIdx.x * 64, k0 = blockIdx.y * 64;
  const float* s = src + (size_t)blockIdx.z * K * N;
  unsigned short* d = dst + (size_t)blockIdx.z * K * N;
  int r = t >> 2, cq = (t & 3) * 16;
#pragma unroll
  for (int i = 0; i < 4; i++) {
    float4 v = *(const float4*)(s + (size_t)(k0 + r) * N + n0 + cq + i * 4);
    tl[r][cq + i * 4 + 0] = v.x;
    tl[r][cq + i * 4 + 1] = v.y;
    tl[r][cq + i * 4 + 2] = v.z;
    tl[r][cq + i * 4 + 3] = v.w;
  }
  __syncthreads();
  int nn = t >> 2, kq = (t & 3) * 16;
#pragma unroll
  for (int half = 0; half < 2; half++) {
    us8 o;
#pragma unroll
    for (int j = 0; j < 8; j++) o[j] = f2bf(tl[kq + half * 8 + j][nn]);
    *(us8*)(d + (size_t)(n0 + nn) * K + k0 + kq + half * 8) = o;
  }
}

// ---------------- weight transpose, 3 (src,dst) pairs picked by z ----------------
__global__ __launch_bounds__(256) void wt3_k(const float* __restrict__ sq,
                                             const float* __restrict__ sk,
                                             const float* __restrict__ sv,
                                             unsigned short* __restrict__ d0,
                                             unsigned short* __restrict__ d1,
                                             unsigned short* __restrict__ d2) {
  __shared__ float tl[64][65];
  int z = blockIdx.z;
  const float* s = (z == 0) ? sq : (z == 1 ? sk : sv);
  unsigned short* d = (z == 0) ? d0 : (z == 1 ? d1 : d2);
  int t = threadIdx.x;
  int n0 = blockIdx.x * 64, k0 = blockIdx.y * 64;
  int r = t >> 2, cq = (t & 3) * 16;
#pragma unroll
  for (int i = 0; i < 4; i++) {
    float4 v = *(const float4*)(s + (size_t)(k0 + r) * DD + n0 + cq + i * 4);
    tl[r][cq + i * 4 + 0] = v.x;
    tl[r][cq + i * 4 + 1] = v.y;
    tl[r][cq + i * 4 + 2] = v.z;
    tl[r][cq + i * 4 + 3] = v.w;
  }
  __syncthreads();
  int nn = t >> 2, kq = (t & 3) * 16;
#pragma unroll
  for (int half = 0; half < 2; half++) {
    us8 o;
#pragma unroll
    for (int j = 0; j < 8; j++) o[j] = f2bf(tl[kq + half * 8 + j][nn]);
    *(us8*)(d + (size_t)(n0 + nn) * DD + k0 + kq + half * 8) = o;
  }
}

// ---------------- elementwise f32 -> bf16 ----------------
__global__ void cvt_k(const float* __restrict__ s, unsigned short* __restrict__ d, int n8) {
  int i = blockIdx.x * blockDim.x + threadIdx.x;
  if (i >= n8) return;
  float4 a = *(const float4*)(s + (size_t)i * 8);
  float4 b = *(const float4*)(s + (size_t)i * 8 + 4);
  us8 o;
  o[0] = f2bf(a.x); o[1] = f2bf(a.y); o[2] = f2bf(a.z); o[3] = f2bf(a.w);
  o[4] = f2bf(b.x); o[5] = f2bf(b.y); o[6] = f2bf(b.z); o[7] = f2bf(b.w);
  *(us8*)(d + (size_t)i * 8) = o;
}

// ---------------- bias concat (all layers, upfront) ----------------
__global__ void bcat_k(const float* __restrict__ bq, const float* __restrict__ bk,
                       const float* __restrict__ bv, float* __restrict__ bqkv1,
                       float* __restrict__ bkv2, float* __restrict__ bqkv3) {
  int i = blockIdx.x * 256 + threadIdx.x;
  if (i >= NLL * 6144) return;
  int l = i / 6144, j = i - l * 6144;
  if (j < 2304) {
    int s = j / 768, c = j - s * 768;
    const float* src = (s == 0) ? bq : (s == 1 ? bk : bv);
    bqkv1[l * 2304 + j] = src[(l * 3 + 0) * 768 + c];
  } else if (j < 3840) {
    int jj = j - 2304;
    int s = jj / 768, c = jj - s * 768;
    bkv2[l * 1536 + jj] = ((s == 0) ? bk : bv)[(l * 3 + 1) * 768 + c];
  } else {
    int jj = j - 3840;
    int s = jj / 768, c = jj - s * 768;
    const float* src = (s == 0) ? bq : (s == 1 ? bk : bv);
    bqkv3[l * 2304 + jj] = src[(l * 3 + 2) * 768 + c];
  }
}

// ---------------- bf16 MFMA GEMM, segmented-A, multi-dest head-major epilogue ----
// A per 768-col segment (seg0: A0, else A1), Bt bf16 [N][K].
// flags: 1=relu, 2=bf16 out, 4=head-major (hd0/1/2 per segment, sh = log2(Sk)).
template <int BM>
__global__ __launch_bounds__(256) void mgemm_k(
    const unsigned short* __restrict__ A0, const unsigned short* __restrict__ A1,
    const unsigned short* __restrict__ Bt, const float* __restrict__ bias,
    const float* __restrict__ res, void* __restrict__ C,
    float* __restrict__ hd0, float* __restrict__ hd1, float* __restrict__ hd2,
    int sh0, int sh1, int sh2, int M, int N, int K, int flags) {
  constexpr int FM = BM / 32;   // 16-row fragments per wave (m-dim)
  constexpr int HB = BM / 2;    // rows per wm half
  __shared__ unsigned short As[BM * 32];
  __shared__ unsigned short Bs[64 * 32];
  int t = threadIdx.x;
  int wave = t >> 6, lane = t & 63;
  int m0 = blockIdx.y * BM, n0 = blockIdx.x * 64;
  int seg = n0 / 768;
  const unsigned short* A = (seg == 0) ? A0 : A1;
  int wm = wave >> 1, wn = wave & 1;
  f32x4 acc[FM][2] = {};
  int aRow = t >> 2, aC8 = (t & 3) * 8;
  const unsigned short* Ab = A + (size_t)m0 * K + aC8;
  const unsigned short* Bb = Bt + (size_t)n0 * K + aC8;
  int aOff0 = (wm * HB + (lane & 15)) * 32 + (lane >> 4) * 8;
  int bOff0 = (wn * 32 + (lane & 15)) * 32 + (lane >> 4) * 8;
  for (int k0 = 0; k0 < K; k0 += 32) {
#pragma unroll
    for (int h = 0; h < BM / 64; h++)
      GLOADLDS16(Ab + (size_t)(h * 64 + aRow) * K + k0, As + h * 2048 + wave * 512);
    GLOADLDS16(Bb + (size_t)aRow * K + k0, Bs + wave * 512);
    __syncthreads();
    bf16x8 aF[FM], bF[2];
#pragma unroll
    for (int fm = 0; fm < FM; fm++)
      aF[fm] = *(const bf16x8*)(As + aOff0 + fm * 16 * 32);
#pragma unroll
    for (int fn = 0; fn < 2; fn++)
      bF[fn] = *(const bf16x8*)(Bs + bOff0 + fn * 16 * 32);
#pragma unroll
    for (int fm = 0; fm < FM; fm++)
#pragma unroll
      for (int fn = 0; fn < 2; fn++)
        acc[fm][fn] = __builtin_amdgcn_mfma_f32_16x16x32_bf16(aF[fm], bF[fn], acc[fm][fn], 0, 0, 0);
    __syncthreads();
  }
  int lcol = lane & 15, lrow4 = (lane >> 4) * 4;
  bool hm = (flags & 4) != 0;
  float* hd = nullptr;
  int sh = 0, segBase = seg * 768;
  if (hm) {
    hd = (seg == 0) ? hd0 : (seg == 1 ? hd1 : hd2);
    sh = (seg == 0) ? sh0 : (seg == 1 ? sh1 : sh2);
  }
#pragma unroll
  for (int fm = 0; fm < FM; fm++) {
#pragma unroll
    for (int fn = 0; fn < 2; fn++) {
      int col = n0 + wn * 32 + fn * 16 + lcol;
      float bv = bias[col];
#pragma unroll
      for (int r = 0; r < 4; r++) {
        int row = m0 + wm * HB + fm * 16 + lrow4 + r;
        float v = acc[fm][fn][r] + bv;
        if (hm) {
          int colr = col - segBase;
          size_t idx = ((((size_t)(row >> sh) * HH + (colr >> 6)) << sh) +
                        (row & ((1 << sh) - 1))) * 64 + (colr & 63);
          hd[idx] = v;
        } else {
          size_t idx = (size_t)row * N + col;
          if (res) v += res[idx];
          if (flags & 1) v = fmaxf(v, 0.f);
          if (flags & 2) ((unsigned short*)C)[idx] = f2bf(v);
          else ((float*)C)[idx] = v;
        }
      }
    }
  }
}

// ---------------- fused attention: head-major K/V, LDS-tiled, bf16 ctx out ----------------
template <int SK>
__global__ __launch_bounds__(256) void attn2_k(const float* __restrict__ qh,
                                               const float* __restrict__ kh,
                                               const float* __restrict__ vh,
                                               unsigned short* __restrict__ ctxb, int mode,
                                               const int* __restrict__ rbuf,
                                               const int* __restrict__ smask) {
  __shared__ float qs[16][68];
  __shared__ float kv[64 * 68];
  __shared__ float ps[16][SK + 4];
  int qt = blockIdx.x, h = blockIdx.y, b = blockIdx.z;
  int t = threadIdx.x;
  size_t kvbase = ((size_t)b * HH + h) * SK * 64;
  {
    int row = t >> 4, c4 = (t & 15) * 4;
    *(float4*)&qs[row][c4] =
        *(const float4*)(qh + (((size_t)b * HH + h) * SS + qt * 16 + row) * 64 + c4);
  }
  int qi = t >> 4, k4 = (t & 15) * 4;
  int qg = qt * 16 + qi;
  int rcut = (mode == 0) ? rbuf[b] : 0;
  for (int kt0 = 0; kt0 < SK / 64; kt0++) {
    if (kt0) __syncthreads();
    {
      int k = t >> 2, d0 = (t & 3) * 16;
      const float* kr = kh + kvbase + (size_t)(kt0 * 64 + k) * 64 + d0;
      float4 a0 = *(const float4*)(kr + 0);
      float4 a1 = *(const float4*)(kr + 4);
      float4 a2 = *(const float4*)(kr + 8);
      float4 a3 = *(const float4*)(kr + 12);
      kv[(d0 + 0) * 64 + k] = a0.x; kv[(d0 + 1) * 64 + k] = a0.y;
      kv[(d0 + 2) * 64 + k] = a0.z; kv[(d0 + 3) * 64 + k] = a0.w;
      kv[(d0 + 4) * 64 + k] = a1.x; kv[(d0 + 5) * 64 + k] = a1.y;
      kv[(d0 + 6) * 64 + k] = a1.z; kv[(d0 + 7) * 64 + k] = a1.w;
      kv[(d0 + 8) * 64 + k] = a2.x; kv[(d0 + 9) * 64 + k] = a2.y;
      kv[(d0 + 10) * 64 + k] = a2.z; kv[(d0 + 11) * 64 + k] = a2.w;
      kv[(d0 + 12) * 64 + k] = a3.x; kv[(d0 + 13) * 64 + k] = a3.y;
      kv[(d0 + 14) * 64 + k] = a3.z; kv[(d0 + 15) * 64 + k] = a3.w;
    }
    __syncthreads();
    float a0 = 0.f, a1 = 0.f, a2 = 0.f, a3 = 0.f;
#pragma unroll
    for (int d = 0; d < 64; d++) {
      float qv = qs[qi][d];
      float4 kvv = *(const float4*)&kv[d * 64 + k4];
      a0 += qv * kvv.x; a1 += qv * kvv.y; a2 += qv * kvv.z; a3 += qv * kvv.w;
    }
    int kb0 = kt0 * 64 + k4;
    float4 sc;
    sc.x = a0 * 0.125f; sc.y = a1 * 0.125f; sc.z = a2 * 0.125f; sc.w = a3 * 0.125f;
    if (mode == 0) {
      bool okq = qg < rcut;
      sc.x = (okq && kb0 + 0 <= qg) ? sc.x : -1e9f;
      sc.y = (okq && kb0 + 1 <= qg) ? sc.y : -1e9f;
      sc.z = (okq && kb0 + 2 <= qg) ? sc.z : -1e9f;
      sc.w = (okq && kb0 + 3 <= qg) ? sc.w : -1e9f;
    } else if (mode == 1) {
      const int* sm = smask + b * SRCC + kb0;
      sc.x = sm[0] ? sc.x : -1e9f;
      sc.y = sm[1] ? sc.y : -1e9f;
      sc.z = sm[2] ? sc.z : -1e9f;
      sc.w = sm[3] ? sc.w : -1e9f;
    }
    *(float4*)&ps[qi][kb0] = sc;
  }
  __syncthreads();
  {
    int row = t >> 4, l16 = t & 15;
    float mx = -3.4e38f;
#pragma unroll
    for (int j = 0; j < SK / 16; j++) mx = fmaxf(mx, ps[row][l16 + 16 * j]);
#pragma unroll
    for (int o = 1; o < 16; o <<= 1) mx = fmaxf(mx, __shfl_xor(mx, o));
    float sum = 0.f;
#pragma unroll
    for (int j = 0; j < SK / 16; j++) {
      int c = l16 + 16 * j;
      float ev = expf(ps[row][c] - mx);
      ps[row][c] = ev;
      sum += ev;
    }
#pragma unroll
    for (int o = 1; o < 16; o <<= 1) sum += __shfl_xor(sum, o);
    float rinv = 1.0f / sum;
#pragma unroll
    for (int j = 0; j < SK / 16; j++) ps[row][l16 + 16 * j] *= rinv;
  }
  float4 acc = make_float4(0.f, 0.f, 0.f, 0.f);
  int d4 = (t & 15) * 4;
  for (int kt0 = 0; kt0 < SK / 64; kt0++) {
    __syncthreads();
    {
      int k = t >> 2, d0 = (t & 3) * 16;
      const float* vr = vh + kvbase + (size_t)(kt0 * 64 + k) * 64 + d0;
      float4 w0 = *(const float4*)(vr + 0);
      float4 w1 = *(const float4*)(vr + 4);
      float4 w2 = *(const float4*)(vr + 8);
      float4 w3 = *(const float4*)(vr + 12);
      *(float4*)&kv[k * 68 + d0 + 0]  = w0;
      *(float4*)&kv[k * 68 + d0 + 4]  = w1;
      *(float4*)&kv[k * 68 + d0 + 8]  = w2;
      *(float4*)&kv[k * 68 + d0 + 12] = w3;
    }
    __syncthreads();
#pragma unroll
    for (int kk = 0; kk < 64; kk++) {
      float p = ps[qi][kt0 * 64 + kk];
      float4 vv = *(const float4*)&kv[kk * 68 + d4];
      acc.x += p * vv.x; acc.y += p * vv.y; acc.z += p * vv.z; acc.w += p * vv.w;
    }
  }
  us4 o;
  o[0] = f2bf(acc.x); o[1] = f2bf(acc.y); o[2] = f2bf(acc.z); o[3] = f2bf(acc.w);
  *(us4*)(ctxb + ((size_t)(b * SS) + qg) * DD + h * 64 + d4) = o;
}

// ---------------- launch ----------------
extern "C" void kernel_launch(void* const* d_in, const int* in_sizes, int n_in,
                              void* d_out, int out_size, void* d_ws, size_t ws_size,
                              hipStream_t stream) {
  const int*   trg   = (const int*)d_in[0];
  const float* e_out = (const float*)d_in[1];
  const int*   smask = (const int*)d_in[2];
  const float* emb   = (const float*)d_in[3];
  const float* ypar  = (const float*)d_in[4];
  const float* alpha = (const float*)d_in[5];
  const float* Wq = (const float*)d_in[6];
  const float* Wk = (const float*)d_in[7];
  const float* Wv = (const float*)d_in[8];
  const float* Wo = (const float*)d_in[9];
  const float* bq = (const float*)d_in[10];
  const float* bk = (const float*)d_in[11];
  const float* bv = (const float*)d_in[12];
  const float* bo = (const float*)d_in[13];
  const float* W1 = (const float*)d_in[14];
  const float* b1 = (const float*)d_in[15];
  const float* W2 = (const float*)d_in[16];
  const float* b2 = (const float*)d_in[17];
  const float* lna = (const float*)d_in[18];
  const float* lnbp = (const float*)d_in[19];
  const float* fa = (const float*)d_in[20];
  const float* fb = (const float*)d_in[21];
  float* out = (float*)d_out;

  float* ws = (float*)d_ws;
  size_t off = 0;
  auto alloc = [&](size_t n) { float* p = ws + off; off += n; return p; };
  const size_t M1 = (size_t)DD * DD;  // 589824
  float* pe  = alloc((size_t)SS * DD);
  int* rbuf  = (int*)alloc(64);
  float* x   = alloc((size_t)BB * SS * DD);
  float* y   = alloc((size_t)BB * SS * DD);
  float* qb  = alloc((size_t)BB * SS * DD);
  float* kb  = alloc((size_t)BB * SRCC * DD);
  float* vb  = alloc((size_t)BB * SRCC * DD);
  float* bqkv1 = alloc((size_t)NLL * 2304);
  float* bkv2  = alloc((size_t)NLL * 1536);
  float* bqkv3 = alloc((size_t)NLL * 2304);
  unsigned short* x2b   = (unsigned short*)alloc((size_t)BB * SS * DD / 2);
  unsigned short* y3b   = (unsigned short*)alloc((size_t)BB * SS * DD / 2);
  unsigned short* ctxb  = (unsigned short*)alloc((size_t)BB * SS * DD / 2);
  unsigned short* midb  = (unsigned short*)alloc((size_t)BB * SS * DFFF / 2);
  unsigned short* eob   = (unsigned short*)alloc((size_t)BB * SRCC * DD / 2);
  unsigned short* wqkv1L = (unsigned short*)alloc(3 * M1 / 2);
  unsigned short* wq2L   = (unsigned short*)alloc(M1 / 2);
  unsigned short* wkv2L  = (unsigned short*)alloc(2 * M1 / 2);
  unsigned short* wqkv3L = (unsigned short*)alloc(3 * M1 / 2);
  unsigned short* wotL   = (unsigned short*)alloc(3 * M1 / 2);
  unsigned short* w1tL   = (unsigned short*)alloc((size_t)DD * DFFF / 2);
  unsigned short* w2tL   = (unsigned short*)alloc((size_t)DFFF * DD / 2);
  if (ws_size < off * sizeof(float)) return;

  pe_build_k<<<(SS * (DD / 2) + 255) / 256, 256, 0, stream>>>(pe);
  embed_k<<<(BB * SS * (DD / 4) + 255) / 256, 256, 0, stream>>>(trg, emb, pe, alpha, x);
  yinit_k<<<(BB * SS * (DD / 4) + 255) / 256, 256, 0, stream>>>(ypar, y);
  mask2_k<<<1, 256, 0, stream>>>(trg, rbuf);
  cvt_k<<<(BB * SRCC * DD / 8 + 255) / 256, 256, 0, stream>>>(e_out, eob, BB * SRCC * DD / 8);
  bcat_k<<<(NLL * 6144 + 255) / 256, 256, 0, stream>>>(bq, bk, bv, bqkv1, bkv2, bqkv3);

  auto MG128 = [&](const unsigned short* A0, const unsigned short* A1, int M, int K,
                   const unsigned short* Bt, int N, const float* bias, const float* res,
                   void* C, float* h0, float* h1, float* h2, int s0, int s1, int s2, int flags) {
    mgemm_k<128><<<dim3(N / 64, M / 128), 256, 0, stream>>>(A0, A1, Bt, bias, res, C,
                                                            h0, h1, h2, s0, s1, s2, M, N, K, flags);
  };
  auto MG64 = [&](const unsigned short* A0, int M, int K,
                  const unsigned short* Bt, int N, const float* bias, const float* res,
                  void* C, float* h0, int s0, int flags) {
    mgemm_k<64><<<dim3(N / 64, M / 64), 256, 0, stream>>>(A0, A0, Bt, bias, res, C,
                                                          h0, nullptr, nullptr, s0, 0, 0, M, N, K, flags);
  };
  const dim3 agrid(SS / 16, HH, BB);

  for (int l = 0; l < NLL; l++) {
    const size_t s3 = (size_t)l * 3 * M1;
    // weight transposes for this layer (fused layouts)
    wt3_k<<<dim3(12, 12, 3), 256, 0, stream>>>(Wq + s3, Wk + s3, Wv + s3,
                                               wqkv1L, wqkv1L + M1, wqkv1L + 2 * M1);
    wt3_k<<<dim3(12, 12, 3), 256, 0, stream>>>(Wq + s3 + M1, Wk + s3 + M1, Wv + s3 + M1,
                                               wq2L, wkv2L, wkv2L + M1);
    wt3_k<<<dim3(12, 12, 3), 256, 0, stream>>>(Wq + s3 + 2 * M1, Wk + s3 + 2 * M1, Wv + s3 + 2 * M1,
                                               wqkv3L, wqkv3L + M1, wqkv3L + 2 * M1);
    wt_k<<<dim3(12, 12, 3), 256, 0, stream>>>(Wo + s3, wotL, DD, DD);
    wt_k<<<dim3(48, 12, 1), 256, 0, stream>>>(W1 + (size_t)l * DD * DFFF, w1tL, DD, DFFF);
    wt_k<<<dim3(12, 48, 1), 256, 0, stream>>>(W2 + (size_t)l * DFFF * DD, w2tL, DFFF, DD);

    auto LNB = [&](const float* in, int slot, unsigned short* o) {
      lnb_k<<<BB * SS, 256, 0, stream>>>(in, lna + ((size_t)l * 5 + slot) * DD,
                                         lnbp + ((size_t)l * 5 + slot) * DD, o);
    };
    // ---- MHA1: self-attn on x (causal + cutoff) ----
    LNB(x, 0, x2b);
    MG128(x2b, x2b, BB * SS, DD, wqkv1L, 2304, bqkv1 + l * 2304, nullptr, nullptr,
          qb, kb, vb, 7, 7, 7, 4);
    attn2_k<SS><<<agrid, 256, 0, stream>>>(qb, kb, vb, ctxb, 0, rbuf, nullptr);
    MG64(ctxb, BB * SS, DD, wotL + 0 * M1, DD, bo + ((size_t)l * 3 + 0) * DD, x, x,
         nullptr, 0, 0);
    // ---- MHA2: y cross-attends e_outputs (src mask) ----
    LNB(y, 1, x2b);
    MG64(x2b, BB * SS, DD, wq2L, DD, bq + ((size_t)l * 3 + 1) * DD, nullptr, nullptr,
         qb, 7, 4);
    MG128(eob, eob, BB * SRCC, DD, wkv2L, 1536, bkv2 + l * 1536, nullptr, nullptr,
          kb, vb, nullptr, 8, 8, 0, 4);
    attn2_k<SRCC><<<agrid, 256, 0, stream>>>(qb, kb, vb, ctxb, 1, nullptr, smask);
    MG64(ctxb, BB * SS, DD, wotL + 1 * M1, DD, bo + ((size_t)l * 3 + 1) * DD, y, y,
         nullptr, 0, 0);
    // ---- MHA3: x cross-attends ln(y) ----
    LNB(x, 2, x2b);
    LNB(y, 3, y3b);
    MG128(x2b, y3b, BB * SS, DD, wqkv3L, 2304, bqkv3 + l * 2304, nullptr, nullptr,
          qb, kb, vb, 7, 7, 7, 4);
    attn2_k<SS><<<agrid, 256, 0, stream>>>(qb, kb, vb, ctxb, 2, nullptr, nullptr);
    MG64(ctxb, BB * SS, DD, wotL + 2 * M1, DD, bo + ((size_t)l * 3 + 2) * DD, x, x,
         nullptr, 0, 0);
    // ---- FFN ----
    LNB(x, 4, x2b);
    MG128(x2b, x2b, BB * SS, DD, w1tL, DFFF, b1 + (size_t)l * DFFF, nullptr, midb,
          nullptr, nullptr, nullptr, 0, 0, 0, 3);
    MG64(midb, BB * SS, DFFF, w2tL, DD, b2 + (size_t)l * DD, x, x, nullptr, 0, 0);
  }
  ln_k<<<BB * SS, 256, 0, stream>>>(x, fa, fb, out);
}

// Round 6
// 1693.145 us; speedup vs baseline: 10.7500x; 1.2229x over previous
//
#include <hip/hip_runtime.h>

#define BB 16
#define SS 128
#define DD 768
#define HH 12
#define DKK 64
#define DFFF 3072
#define NLL 6
#define SRCC 256

typedef short bf16x8 __attribute__((ext_vector_type(8)));
typedef float f32x4 __attribute__((ext_vector_type(4)));
typedef unsigned short us8 __attribute__((ext_vector_type(8)));
typedef unsigned short us4 __attribute__((ext_vector_type(4)));

__device__ __forceinline__ unsigned short f2bf(float f) {
  unsigned int u = __builtin_bit_cast(unsigned int, f);
  u = (u + 0x7fff + ((u >> 16) & 1)) >> 16;
  return (unsigned short)u;
}

#define GLOADLDS16(gp, lp)                                              \
  __builtin_amdgcn_global_load_lds(                                     \
      (const __attribute__((address_space(1))) void*)(gp),              \
      (__attribute__((address_space(3))) void*)(lp), 16, 0, 0)

// ---------------- positional encoding table ----------------
__global__ void pe_build_k(float* __restrict__ pe) {
  int idx = blockIdx.x * blockDim.x + threadIdx.x;
  if (idx >= SS * (DD / 2)) return;
  int s = idx / (DD / 2);
  int i = idx - s * (DD / 2);
  float div = expf((float)(2 * i) * (-logf(10000.0f) / (float)DD));
  float ang = (float)s * div;
  pe[s * DD + 2 * i]     = sinf(ang);
  pe[s * DD + 2 * i + 1] = cosf(ang);
}

// ---------------- x = emb[trg] + alpha * pe ----------------
__global__ void embed_k(const int* __restrict__ trg, const float* __restrict__ emb,
                        const float* __restrict__ pe, const float* __restrict__ alpha,
                        float* __restrict__ x) {
  int idx = blockIdx.x * blockDim.x + threadIdx.x;
  int c = idx % (DD / 4);
  int r = idx / (DD / 4);
  if (r >= BB * SS) return;
  int s = r % SS;
  float al = alpha[0];
  float4 e = *(const float4*)(emb + (size_t)trg[r] * DD + c * 4);
  float4 p = *(const float4*)(pe + (size_t)s * DD + c * 4);
  float4 o;
  o.x = e.x + al * p.x; o.y = e.y + al * p.y;
  o.z = e.z + al * p.z; o.w = e.w + al * p.w;
  *(float4*)(x + (size_t)r * DD + c * 4) = o;
}

// ---------------- y = broadcast(y_param) ----------------
__global__ void yinit_k(const float* __restrict__ yp, float* __restrict__ y) {
  int idx = blockIdx.x * blockDim.x + threadIdx.x;
  int c = idx % (DD / 4);
  int r = idx / (DD / 4);
  if (r >= BB * SS) return;
  int s = r % SS;
  *(float4*)(y + (size_t)r * DD + c * 4) = *(const float4*)(yp + (size_t)s * DD + c * 4);
}

// ---------------- combined mask cutoff r[b] (parallel) ----------------
__global__ void mask2_k(const int* __restrict__ trg, int* __restrict__ rbuf) {
  __shared__ int first[BB];
  int t = threadIdx.x;
  if (t < BB) first[t] = 0x7fffffff;
  __syncthreads();
  int b = t >> 4, p0 = (t & 15) * 8;
  int loc = 0x7fffffff;
#pragma unroll
  for (int i = 0; i < 8; i++) {
    if (trg[b * SS + p0 + i] == 0) { loc = p0 + i; break; }
  }
  atomicMin(&first[b], loc);
  __syncthreads();
  if (t == 0) {
    int cmin = 0x7fffffff;
    int cm[BB];
    for (int bb = 0; bb < BB; bb++) {
      int start = (first[bb] == 0x7fffffff) ? 0 : first[bb];
      int c = (start == 0) ? (SS + 1) : start;
      cmin = min(cmin, c);
      cm[bb] = cmin;
    }
    for (int bb = 0; bb < BB; bb++) rbuf[bb] = cm[min(bb, BB - 2)];
  }
}

// ---------------- LayerNorm f32-out (final) ----------------
__global__ __launch_bounds__(256) void ln_k(const float* __restrict__ x,
                                            const float* __restrict__ ga,
                                            const float* __restrict__ gb,
                                            float* __restrict__ out) {
  __shared__ float sm[8];
  int row = blockIdx.x;
  int t = threadIdx.x;
  const float* xr = x + (size_t)row * DD;
  float v0 = xr[t], v1 = xr[t + 256], v2 = xr[t + 512];
  float s = v0 + v1 + v2;
#pragma unroll
  for (int o = 32; o > 0; o >>= 1) s += __shfl_down(s, o);
  if ((t & 63) == 0) sm[t >> 6] = s;
  __syncthreads();
  float mean = (sm[0] + sm[1] + sm[2] + sm[3]) * (1.0f / (float)DD);
  float d0 = v0 - mean, d1 = v1 - mean, d2 = v2 - mean;
  float q = d0 * d0 + d1 * d1 + d2 * d2;
#pragma unroll
  for (int o = 32; o > 0; o >>= 1) q += __shfl_down(q, o);
  if ((t & 63) == 0) sm[4 + (t >> 6)] = q;
  __syncthreads();
  float var = (sm[4] + sm[5] + sm[6] + sm[7]) * (1.0f / (float)DD);
  float inv = 1.0f / sqrtf(var + 1e-6f);
  float* orow = out + (size_t)row * DD;
  orow[t]       = ga[t] * d0 * inv + gb[t];
  orow[t + 256] = ga[t + 256] * d1 * inv + gb[t + 256];
  orow[t + 512] = ga[t + 512] * d2 * inv + gb[t + 512];
}

// ---------------- LayerNorm bf16-out ----------------
__global__ __launch_bounds__(256) void lnb_k(const float* __restrict__ x,
                                             const float* __restrict__ ga,
                                             const float* __restrict__ gb,
                                             unsigned short* __restrict__ out) {
  __shared__ float sm[8];
  int row = blockIdx.x;
  int t = threadIdx.x;
  const float* xr = x + (size_t)row * DD;
  float v0 = xr[t], v1 = xr[t + 256], v2 = xr[t + 512];
  float s = v0 + v1 + v2;
#pragma unroll
  for (int o = 32; o > 0; o >>= 1) s += __shfl_down(s, o);
  if ((t & 63) == 0) sm[t >> 6] = s;
  __syncthreads();
  float mean = (sm[0] + sm[1] + sm[2] + sm[3]) * (1.0f / (float)DD);
  float d0 = v0 - mean, d1 = v1 - mean, d2 = v2 - mean;
  float q = d0 * d0 + d1 * d1 + d2 * d2;
#pragma unroll
  for (int o = 32; o > 0; o >>= 1) q += __shfl_down(q, o);
  if ((t & 63) == 0) sm[4 + (t >> 6)] = q;
  __syncthreads();
  float var = (sm[4] + sm[5] + sm[6] + sm[7]) * (1.0f / (float)DD);
  float inv = 1.0f / sqrtf(var + 1e-6f);
  unsigned short* orow = out + (size_t)row * DD;
  orow[t]       = f2bf(ga[t] * d0 * inv + gb[t]);
  orow[t + 256] = f2bf(ga[t + 256] * d1 * inv + gb[t + 256]);
  orow[t + 512] = f2bf(ga[t + 512] * d2 * inv + gb[t + 512]);
}

// ---------------- weight transpose: f32 [K][N] -> bf16 [N][K], z strided K*N ----------------
__global__ __launch_bounds__(256) void wt_k(const float* __restrict__ src,
                                            unsigned short* __restrict__ dst,
                                            int K, int N) {
  __shared__ float tl[64][65];
  int t = threadIdx.x;
  int n0 = blockIdx.x * 64, k0 = blockIdx.y * 64;
  const float* s = src + (size_t)blockIdx.z * K * N;
  unsigned short* d = dst + (size_t)blockIdx.z * K * N;
  int r = t >> 2, cq = (t & 3) * 16;
#pragma unroll
  for (int i = 0; i < 4; i++) {
    float4 v = *(const float4*)(s + (size_t)(k0 + r) * N + n0 + cq + i * 4);
    tl[r][cq + i * 4 + 0] = v.x;
    tl[r][cq + i * 4 + 1] = v.y;
    tl[r][cq + i * 4 + 2] = v.z;
    tl[r][cq + i * 4 + 3] = v.w;
  }
  __syncthreads();
  int nn = t >> 2, kq = (t & 3) * 16;
#pragma unroll
  for (int half = 0; half < 2; half++) {
    us8 o;
#pragma unroll
    for (int j = 0; j < 8; j++) o[j] = f2bf(tl[kq + half * 8 + j][nn]);
    *(us8*)(d + (size_t)(n0 + nn) * K + k0 + kq + half * 8) = o;
  }
}

// ---------------- weight transpose, 3 (src,dst) pairs picked by z ----------------
__global__ __launch_bounds__(256) void wt3_k(const float* __restrict__ sq,
                                             const float* __restrict__ sk,
                                             const float* __restrict__ sv,
                                             unsigned short* __restrict__ d0,
                                             unsigned short* __restrict__ d1,
                                             unsigned short* __restrict__ d2) {
  __shared__ float tl[64][65];
  int z = blockIdx.z;
  const float* s = (z == 0) ? sq : (z == 1 ? sk : sv);
  unsigned short* d = (z == 0) ? d0 : (z == 1 ? d1 : d2);
  int t = threadIdx.x;
  int n0 = blockIdx.x * 64, k0 = blockIdx.y * 64;
  int r = t >> 2, cq = (t & 3) * 16;
#pragma unroll
  for (int i = 0; i < 4; i++) {
    float4 v = *(const float4*)(s + (size_t)(k0 + r) * DD + n0 + cq + i * 4);
    tl[r][cq + i * 4 + 0] = v.x;
    tl[r][cq + i * 4 + 1] = v.y;
    tl[r][cq + i * 4 + 2] = v.z;
    tl[r][cq + i * 4 + 3] = v.w;
  }
  __syncthreads();
  int nn = t >> 2, kq = (t & 3) * 16;
#pragma unroll
  for (int half = 0; half < 2; half++) {
    us8 o;
#pragma unroll
    for (int j = 0; j < 8; j++) o[j] = f2bf(tl[kq + half * 8 + j][nn]);
    *(us8*)(d + (size_t)(n0 + nn) * DD + k0 + kq + half * 8) = o;
  }
}

// ---------------- elementwise f32 -> bf16 ----------------
__global__ void cvt_k(const float* __restrict__ s, unsigned short* __restrict__ d, int n8) {
  int i = blockIdx.x * blockDim.x + threadIdx.x;
  if (i >= n8) return;
  float4 a = *(const float4*)(s + (size_t)i * 8);
  float4 b = *(const float4*)(s + (size_t)i * 8 + 4);
  us8 o;
  o[0] = f2bf(a.x); o[1] = f2bf(a.y); o[2] = f2bf(a.z); o[3] = f2bf(a.w);
  o[4] = f2bf(b.x); o[5] = f2bf(b.y); o[6] = f2bf(b.z); o[7] = f2bf(b.w);
  *(us8*)(d + (size_t)i * 8) = o;
}

// ---------------- bias concat (all layers, upfront) ----------------
__global__ void bcat_k(const float* __restrict__ bq, const float* __restrict__ bk,
                       const float* __restrict__ bv, float* __restrict__ bqkv1,
                       float* __restrict__ bkv2, float* __restrict__ bqkv3) {
  int i = blockIdx.x * 256 + threadIdx.x;
  if (i >= NLL * 6144) return;
  int l = i / 6144, j = i - l * 6144;
  if (j < 2304) {
    int s = j / 768, c = j - s * 768;
    const float* src = (s == 0) ? bq : (s == 1 ? bk : bv);
    bqkv1[l * 2304 + j] = src[(l * 3 + 0) * 768 + c];
  } else if (j < 3840) {
    int jj = j - 2304;
    int s = jj / 768, c = jj - s * 768;
    bkv2[l * 1536 + jj] = ((s == 0) ? bk : bv)[(l * 3 + 1) * 768 + c];
  } else {
    int jj = j - 3840;
    int s = jj / 768, c = jj - s * 768;
    const float* src = (s == 0) ? bq : (s == 1 ? bk : bv);
    bqkv3[l * 2304 + jj] = src[(l * 3 + 2) * 768 + c];
  }
}

// ---------------- bf16 MFMA GEMM, segmented-A, multi-dest head-major epilogue ----
// flags: 1=relu, 2=bf16 out, 4=head-major bf16 (hd0/1/2 per 768-col segment,
// sh = log2(Sk); vtbits bit set -> transposed [B,H,64,Sk] layout).
template <int BM>
__global__ __launch_bounds__(256) void mgemm_k(
    const unsigned short* __restrict__ A0, const unsigned short* __restrict__ A1,
    const unsigned short* __restrict__ Bt, const float* __restrict__ bias,
    const float* __restrict__ res, void* __restrict__ C,
    unsigned short* __restrict__ hd0, unsigned short* __restrict__ hd1,
    unsigned short* __restrict__ hd2,
    int sh0, int sh1, int sh2, int M, int N, int K, int flags, int vtbits) {
  constexpr int FM = BM / 32;
  constexpr int HB = BM / 2;
  __shared__ unsigned short As[BM * 32];
  __shared__ unsigned short Bs[64 * 32];
  int t = threadIdx.x;
  int wave = t >> 6, lane = t & 63;
  int m0 = blockIdx.y * BM, n0 = blockIdx.x * 64;
  int seg = n0 / 768;
  const unsigned short* A = (seg == 0) ? A0 : A1;
  int wm = wave >> 1, wn = wave & 1;
  f32x4 acc[FM][2] = {};
  int aRow = t >> 2, aC8 = (t & 3) * 8;
  const unsigned short* Ab = A + (size_t)m0 * K + aC8;
  const unsigned short* Bb = Bt + (size_t)n0 * K + aC8;
  int aOff0 = (wm * HB + (lane & 15)) * 32 + (lane >> 4) * 8;
  int bOff0 = (wn * 32 + (lane & 15)) * 32 + (lane >> 4) * 8;
  for (int k0 = 0; k0 < K; k0 += 32) {
#pragma unroll
    for (int h = 0; h < BM / 64; h++)
      GLOADLDS16(Ab + (size_t)(h * 64 + aRow) * K + k0, As + h * 2048 + wave * 512);
    GLOADLDS16(Bb + (size_t)aRow * K + k0, Bs + wave * 512);
    __syncthreads();
    bf16x8 aF[FM], bF[2];
#pragma unroll
    for (int fm = 0; fm < FM; fm++)
      aF[fm] = *(const bf16x8*)(As + aOff0 + fm * 16 * 32);
#pragma unroll
    for (int fn = 0; fn < 2; fn++)
      bF[fn] = *(const bf16x8*)(Bs + bOff0 + fn * 16 * 32);
#pragma unroll
    for (int fm = 0; fm < FM; fm++)
#pragma unroll
      for (int fn = 0; fn < 2; fn++)
        acc[fm][fn] = __builtin_amdgcn_mfma_f32_16x16x32_bf16(aF[fm], bF[fn], acc[fm][fn], 0, 0, 0);
    __syncthreads();
  }
  int lcol = lane & 15, lrow4 = (lane >> 4) * 4;
  bool hm = (flags & 4) != 0;
  unsigned short* hd = nullptr;
  int sh = 0, segBase = seg * 768, vtseg = 0;
  if (hm) {
    hd = (seg == 0) ? hd0 : (seg == 1 ? hd1 : hd2);
    sh = (seg == 0) ? sh0 : (seg == 1 ? sh1 : sh2);
    vtseg = (vtbits >> seg) & 1;
  }
#pragma unroll
  for (int fm = 0; fm < FM; fm++) {
#pragma unroll
    for (int fn = 0; fn < 2; fn++) {
      int col = n0 + wn * 32 + fn * 16 + lcol;
      float bv = bias[col];
      int rowb = m0 + wm * HB + fm * 16 + lrow4;
      if (hm) {
        int colr = col - segBase;
        int hh = colr >> 6, dd = colr & 63;
        int bb = rowb >> sh, ssb = rowb & ((1 << sh) - 1);
        if (vtseg) {
          // [B,H,64,Sk] transposed: 4 consecutive rows -> contiguous k
          size_t idx = (((size_t)bb * HH + hh) * 64 + dd) * (size_t)(1 << sh) + ssb;
          us4 pk;
#pragma unroll
          for (int r = 0; r < 4; r++) pk[r] = f2bf(acc[fm][fn][r] + bv);
          *(us4*)(hd + idx) = pk;
        } else {
          size_t base = ((((size_t)bb * HH + hh) << sh) + ssb) * 64 + dd;
#pragma unroll
          for (int r = 0; r < 4; r++) hd[base + (size_t)r * 64] = f2bf(acc[fm][fn][r] + bv);
        }
      } else {
#pragma unroll
        for (int r = 0; r < 4; r++) {
          int row = rowb + r;
          float v = acc[fm][fn][r] + bv;
          size_t idx = (size_t)row * N + col;
          if (res) v += res[idx];
          if (flags & 1) v = fmaxf(v, 0.f);
          if (flags & 2) ((unsigned short*)C)[idx] = f2bf(v);
          else ((float*)C)[idx] = v;
        }
      }
    }
  }
}

// ---------------- MFMA flash attention ----------------
// qh bf16 [B,H,S,64]; kh bf16 [B,H,SK,64]; vth bf16 [B,H,64,SK] (transposed).
// grid (S/64, H, B), 256 thr / 4 waves; wave w owns q-rows qhalf*64 + w*16 ..+16.
// mode: 0=causal+cutoff, 1=src_mask, 2=none. ctx out bf16 [B,S,D].
template <int SK>
__global__ __launch_bounds__(256) void attn3_k(const unsigned short* __restrict__ qh,
                                               const unsigned short* __restrict__ kh,
                                               const unsigned short* __restrict__ vth,
                                               unsigned short* __restrict__ ctxb, int mode,
                                               const int* __restrict__ rbuf,
                                               const int* __restrict__ smask) {
  constexpr int NPH = SK / 128;          // staging phases (1 or 2)
  constexpr int NF = SK / 16;            // score fragments per wave
  __shared__ unsigned short kvb[128 * 72];        // K rows [128][72] / Vt [64][136] union
  __shared__ unsigned short pbuf[64 * (SK + 8)];  // P [64][SK+8]
  int qhalf = blockIdx.x, h = blockIdx.y, b = blockIdx.z;
  int t = threadIdx.x;
  int wave = t >> 6, lane = t & 63;
  int l15 = lane & 15, lhi = lane >> 4;
  int qrow0 = qhalf * 64 + wave * 16;    // this wave's first global q row
  size_t bh = (size_t)b * HH + h;
  // Q fragments from global (A-operand: row=lane&15, k=(lane>>4)*8, 2 k-steps)
  bf16x8 aQ[2];
#pragma unroll
  for (int ks = 0; ks < 2; ks++)
    aQ[ks] = *(const bf16x8*)(qh + (bh * SS + qrow0 + l15) * 64 + ks * 32 + lhi * 8);
  f32x4 accS[NF] = {};
  // ---- scores: S = Q K^T ----
  const unsigned short* kbase = kh + bh * SK * 64;
  for (int ph = 0; ph < NPH; ph++) {
    if (ph) __syncthreads();
    {
      int c0 = t * 4;  // 128 rows x 8 chunks(16B) = 1024 chunks
#pragma unroll
      for (int i = 0; i < 4; i++) {
        int c = c0 + i, row = c >> 3, co = (c & 7) * 8;
        *(us8*)&kvb[row * 72 + co] = *(const us8*)(kbase + (size_t)(ph * 128 + row) * 64 + co);
      }
    }
    __syncthreads();
#pragma unroll
    for (int kf = 0; kf < 8; kf++) {
      int gf = ph * 8 + kf;
#pragma unroll
      for (int ks = 0; ks < 2; ks++) {
        bf16x8 bK = *(const bf16x8*)(&kvb[(kf * 16 + l15) * 72 + ks * 32 + lhi * 8]);
        accS[gf] = __builtin_amdgcn_mfma_f32_16x16x32_bf16(aQ[ks], bK, accS[gf], 0, 0, 0);
      }
    }
  }
  // ---- mask + softmax (row q = qrow0 + lhi*4 + r, col k = gf*16 + l15) ----
  int rcut = (mode == 0) ? rbuf[b] : 0;
#pragma unroll
  for (int r = 0; r < 4; r++) {
    int qg = qrow0 + lhi * 4 + r;
    float mx = -3.4e38f;
#pragma unroll
    for (int gf = 0; gf < NF; gf++) {
      int k = gf * 16 + l15;
      float s = accS[gf][r] * 0.125f;
      bool keep = true;
      if (mode == 0) keep = (k <= qg) && (qg < rcut);
      else if (mode == 1) keep = (smask[b * SRCC + k] != 0);
      s = keep ? s : -1e9f;
      accS[gf][r] = s;
      mx = fmaxf(mx, s);
    }
#pragma unroll
    for (int o = 1; o < 16; o <<= 1) mx = fmaxf(mx, __shfl_xor(mx, o));
    float sum = 0.f;
#pragma unroll
    for (int gf = 0; gf < NF; gf++) {
      float e = expf(accS[gf][r] - mx);
      accS[gf][r] = e;
      sum += e;
    }
#pragma unroll
    for (int o = 1; o < 16; o <<= 1) sum += __shfl_xor(sum, o);
    float rinv = 1.0f / sum;
#pragma unroll
    for (int gf = 0; gf < NF; gf++) accS[gf][r] *= rinv;
  }
  // ---- write P bf16 to LDS ----
#pragma unroll
  for (int gf = 0; gf < NF; gf++) {
#pragma unroll
    for (int r = 0; r < 4; r++) {
      int ql = wave * 16 + lhi * 4 + r;
      pbuf[ql * (SK + 8) + gf * 16 + l15] = f2bf(accS[gf][r]);
    }
  }
  __syncthreads();
  // ---- PV: O = P V  (Vt [64][SK] staged in k-halves of 128) ----
  f32x4 accO[4] = {};
  const unsigned short* vbase = vth + bh * 64 * SK;
  for (int ph = 0; ph < NPH; ph++) {
    if (ph) __syncthreads();
    {
      int c0 = t * 4;  // 64 rows x 16 chunks(16B) = 1024 chunks per phase
#pragma unroll
      for (int i = 0; i < 4; i++) {
        int c = c0 + i, row = c >> 4, co = (c & 15) * 8;
        *(us8*)&kvb[row * 136 + co] = *(const us8*)(vbase + (size_t)row * SK + ph * 128 + co);
      }
    }
    __syncthreads();
#pragma unroll
    for (int ks = 0; ks < 4; ks++) {
      bf16x8 aP = *(const bf16x8*)(&pbuf[(wave * 16 + l15) * (SK + 8) + ph * 128 + ks * 32 + lhi * 8]);
#pragma unroll
      for (int nf = 0; nf < 4; nf++) {
        bf16x8 bV = *(const bf16x8*)(&kvb[(nf * 16 + l15) * 136 + ks * 32 + lhi * 8]);
        accO[nf] = __builtin_amdgcn_mfma_f32_16x16x32_bf16(aP, bV, accO[nf], 0, 0, 0);
      }
    }
  }
  // ---- write ctx bf16 [B,S,D] ----
#pragma unroll
  for (int nf = 0; nf < 4; nf++) {
#pragma unroll
    for (int r = 0; r < 4; r++) {
      int qg = qrow0 + lhi * 4 + r;
      ctxb[((size_t)b * SS + qg) * DD + h * 64 + nf * 16 + l15] = f2bf(accO[nf][r]);
    }
  }
}

// ---------------- launch ----------------
extern "C" void kernel_launch(void* const* d_in, const int* in_sizes, int n_in,
                              void* d_out, int out_size, void* d_ws, size_t ws_size,
                              hipStream_t stream) {
  const int*   trg   = (const int*)d_in[0];
  const float* e_out = (const float*)d_in[1];
  const int*   smask = (const int*)d_in[2];
  const float* emb   = (const float*)d_in[3];
  const float* ypar  = (const float*)d_in[4];
  const float* alpha = (const float*)d_in[5];
  const float* Wq = (const float*)d_in[6];
  const float* Wk = (const float*)d_in[7];
  const float* Wv = (const float*)d_in[8];
  const float* Wo = (const float*)d_in[9];
  const float* bq = (const float*)d_in[10];
  const float* bk = (const float*)d_in[11];
  const float* bv = (const float*)d_in[12];
  const float* bo = (const float*)d_in[13];
  const float* W1 = (const float*)d_in[14];
  const float* b1 = (const float*)d_in[15];
  const float* W2 = (const float*)d_in[16];
  const float* b2 = (const float*)d_in[17];
  const float* lna = (const float*)d_in[18];
  const float* lnbp = (const float*)d_in[19];
  const float* fa = (const float*)d_in[20];
  const float* fb = (const float*)d_in[21];
  float* out = (float*)d_out;

  float* ws = (float*)d_ws;
  size_t off = 0;
  auto alloc = [&](size_t n) { float* p = ws + off; off += n; return p; };
  const size_t M1 = (size_t)DD * DD;
  float* pe  = alloc((size_t)SS * DD);
  int* rbuf  = (int*)alloc(64);
  float* x   = alloc((size_t)BB * SS * DD);
  float* y   = alloc((size_t)BB * SS * DD);
  float* bqkv1 = alloc((size_t)NLL * 2304);
  float* bkv2  = alloc((size_t)NLL * 1536);
  float* bqkv3 = alloc((size_t)NLL * 2304);
  unsigned short* qhb  = (unsigned short*)alloc((size_t)BB * HH * SS * DKK / 2);
  unsigned short* khb  = (unsigned short*)alloc((size_t)BB * HH * SRCC * DKK / 2);
  unsigned short* vthb = (unsigned short*)alloc((size_t)BB * HH * SRCC * DKK / 2);
  unsigned short* x2b   = (unsigned short*)alloc((size_t)BB * SS * DD / 2);
  unsigned short* y3b   = (unsigned short*)alloc((size_t)BB * SS * DD / 2);
  unsigned short* ctxb  = (unsigned short*)alloc((size_t)BB * SS * DD / 2);
  unsigned short* midb  = (unsigned short*)alloc((size_t)BB * SS * DFFF / 2);
  unsigned short* eob   = (unsigned short*)alloc((size_t)BB * SRCC * DD / 2);
  unsigned short* wqkv1L = (unsigned short*)alloc(3 * M1 / 2);
  unsigned short* wq2L   = (unsigned short*)alloc(M1 / 2);
  unsigned short* wkv2L  = (unsigned short*)alloc(2 * M1 / 2);
  unsigned short* wqkv3L = (unsigned short*)alloc(3 * M1 / 2);
  unsigned short* wotL   = (unsigned short*)alloc(3 * M1 / 2);
  unsigned short* w1tL   = (unsigned short*)alloc((size_t)DD * DFFF / 2);
  unsigned short* w2tL   = (unsigned short*)alloc((size_t)DFFF * DD / 2);
  if (ws_size < off * sizeof(float)) return;

  pe_build_k<<<(SS * (DD / 2) + 255) / 256, 256, 0, stream>>>(pe);
  embed_k<<<(BB * SS * (DD / 4) + 255) / 256, 256, 0, stream>>>(trg, emb, pe, alpha, x);
  yinit_k<<<(BB * SS * (DD / 4) + 255) / 256, 256, 0, stream>>>(ypar, y);
  mask2_k<<<1, 256, 0, stream>>>(trg, rbuf);
  cvt_k<<<(BB * SRCC * DD / 8 + 255) / 256, 256, 0, stream>>>(e_out, eob, BB * SRCC * DD / 8);
  bcat_k<<<(NLL * 6144 + 255) / 256, 256, 0, stream>>>(bq, bk, bv, bqkv1, bkv2, bqkv3);

  auto MG128 = [&](const unsigned short* A0, const unsigned short* A1, int M, int K,
                   const unsigned short* Bt, int N, const float* bias, const float* res,
                   void* C, unsigned short* h0, unsigned short* h1, unsigned short* h2,
                   int s0, int s1, int s2, int flags, int vtb) {
    mgemm_k<128><<<dim3(N / 64, M / 128), 256, 0, stream>>>(A0, A1, Bt, bias, res, C,
                                                            h0, h1, h2, s0, s1, s2, M, N, K, flags, vtb);
  };
  auto MG64 = [&](const unsigned short* A0, int M, int K,
                  const unsigned short* Bt, int N, const float* bias, const float* res,
                  void* C, unsigned short* h0, int s0, int flags, int vtb) {
    mgemm_k<64><<<dim3(N / 64, M / 64), 256, 0, stream>>>(A0, A0, Bt, bias, res, C,
                                                          h0, nullptr, nullptr, s0, 0, 0, M, N, K, flags, vtb);
  };
  const dim3 agrid(SS / 64, HH, BB);

  for (int l = 0; l < NLL; l++) {
    const size_t s3 = (size_t)l * 3 * M1;
    wt3_k<<<dim3(12, 12, 3), 256, 0, stream>>>(Wq + s3, Wk + s3, Wv + s3,
                                               wqkv1L, wqkv1L + M1, wqkv1L + 2 * M1);
    wt3_k<<<dim3(12, 12, 3), 256, 0, stream>>>(Wq + s3 + M1, Wk + s3 + M1, Wv + s3 + M1,
                                               wq2L, wkv2L, wkv2L + M1);
    wt3_k<<<dim3(12, 12, 3), 256, 0, stream>>>(Wq + s3 + 2 * M1, Wk + s3 + 2 * M1, Wv + s3 + 2 * M1,
                                               wqkv3L, wqkv3L + M1, wqkv3L + 2 * M1);
    wt_k<<<dim3(12, 12, 3), 256, 0, stream>>>(Wo + s3, wotL, DD, DD);
    wt_k<<<dim3(48, 12, 1), 256, 0, stream>>>(W1 + (size_t)l * DD * DFFF, w1tL, DD, DFFF);
    wt_k<<<dim3(12, 48, 1), 256, 0, stream>>>(W2 + (size_t)l * DFFF * DD, w2tL, DFFF, DD);

    auto LNB = [&](const float* in, int slot, unsigned short* o) {
      lnb_k<<<BB * SS, 256, 0, stream>>>(in, lna + ((size_t)l * 5 + slot) * DD,
                                         lnbp + ((size_t)l * 5 + slot) * DD, o);
    };
    // ---- MHA1: self-attn on x (causal + cutoff) ----
    LNB(x, 0, x2b);
    MG128(x2b, x2b, BB * SS, DD, wqkv1L, 2304, bqkv1 + l * 2304, nullptr, nullptr,
          qhb, khb, vthb, 7, 7, 7, 4, 0b100);
    attn3_k<SS><<<agrid, 256, 0, stream>>>(qhb, khb, vthb, ctxb, 0, rbuf, nullptr);
    MG64(ctxb, BB * SS, DD, wotL + 0 * M1, DD, bo + ((size_t)l * 3 + 0) * DD, x, x,
         nullptr, 0, 0, 0);
    // ---- MHA2: y cross-attends e_outputs (src mask) ----
    LNB(y, 1, x2b);
    MG64(x2b, BB * SS, DD, wq2L, DD, bq + ((size_t)l * 3 + 1) * DD, nullptr, nullptr,
         qhb, 7, 4, 0);
    MG128(eob, eob, BB * SRCC, DD, wkv2L, 1536, bkv2 + l * 1536, nullptr, nullptr,
          khb, vthb, nullptr, 8, 8, 0, 4, 0b10);
    attn3_k<SRCC><<<agrid, 256, 0, stream>>>(qhb, khb, vthb, ctxb, 1, nullptr, smask);
    MG64(ctxb, BB * SS, DD, wotL + 1 * M1, DD, bo + ((size_t)l * 3 + 1) * DD, y, y,
         nullptr, 0, 0, 0);
    // ---- MHA3: x cross-attends ln(y) ----
    LNB(x, 2, x2b);
    LNB(y, 3, y3b);
    MG128(x2b, y3b, BB * SS, DD, wqkv3L, 2304, bqkv3 + l * 2304, nullptr, nullptr,
          qhb, khb, vthb, 7, 7, 7, 4, 0b100);
    attn3_k<SS><<<agrid, 256, 0, stream>>>(qhb, khb, vthb, ctxb, 2, nullptr, nullptr);
    MG64(ctxb, BB * SS, DD, wotL + 2 * M1, DD, bo + ((size_t)l * 3 + 2) * DD, x, x,
         nullptr, 0, 0, 0);
    // ---- FFN ----
    LNB(x, 4, x2b);
    MG128(x2b, x2b, BB * SS, DD, w1tL, DFFF, b1 + (size_t)l * DFFF, nullptr, midb,
          nullptr, nullptr, nullptr, 0, 0, 0, 3, 0);
    MG64(midb, BB * SS, DFFF, w2tL, DD, b2 + (size_t)l * DD, x, x, nullptr, 0, 0, 0);
  }
  ln_k<<<BB * SS, 256, 0, stream>>>(x, fa, fb, out);
}